// Round 1
// baseline (3953.540 us; speedup 1.0000x reference)
//
#include <hip/hip_runtime.h>

// Problem constants (fixed by the reference's setup_inputs)
constexpr int N = 40000;    // nodes
constexpr int E = 640000;   // edges
constexpr int G = 64;       // graphs
constexpr int H = 128;      // hidden = F_IN

// ---------------------------------------------------------------------------
// zero-fill (avoid hipMemsetAsync inside capture just to be safe)
__global__ void zero_f32(float* __restrict__ p, int n) {
    int i = blockIdx.x * blockDim.x + threadIdx.x;
    if (i < n) p[i] = 0.0f;
}

// deg[col[e]] += 1 for each edge (self-loop +1 added in finalize)
__global__ void count_deg(const int* __restrict__ col, float* __restrict__ deg) {
    int e = blockIdx.x * blockDim.x + threadIdx.x;
    if (e < E) atomicAdd(&deg[col[e]], 1.0f);
}

// dis[i] = rsqrt(deg[i] + 1)   (self-loop guarantees deg >= 1)
__global__ void finalize_dis(float* __restrict__ deg_dis) {
    int i = blockIdx.x * blockDim.x + threadIdx.x;
    if (i < N) deg_dis[i] = rsqrtf(deg_dis[i] + 1.0f);
}

// norm[e] = dis[row[e]] * dis[col[e]]
__global__ void compute_norm(const int* __restrict__ row, const int* __restrict__ col,
                             const float* __restrict__ dis, float* __restrict__ norm) {
    int e = blockIdx.x * blockDim.x + threadIdx.x;
    if (e < E) norm[e] = dis[row[e]] * dis[col[e]];
}

// ---------------------------------------------------------------------------
// Y[r][j] = sum_k relu?(X[r][k]) * W[k][j] + b[j]
// Block: 256 threads = 2 rows x 128 cols per iteration, 32 rows per block.
// W (64 KB) staged in LDS; x row read as broadcast float4 loads.
template <bool RELU_IN>
__global__ __launch_bounds__(256) void gemm_bias(const float* __restrict__ X,
                                                 const float* __restrict__ W,
                                                 const float* __restrict__ b,
                                                 float* __restrict__ Y) {
    __shared__ float Ws[H * H];   // 64 KB
    const int tid = threadIdx.x;
    #pragma unroll 4
    for (int i = 0; i < (H * H) / 256; ++i) Ws[tid + i * 256] = W[tid + i * 256];
    const int j  = tid & 127;
    const int rh = tid >> 7;   // 0 or 1
    const float bj = b[j];
    __syncthreads();

    const int row0 = blockIdx.x * 32;
    for (int rr = 0; rr < 32; rr += 2) {
        const int r = row0 + rr + rh;
        const float4* xr = reinterpret_cast<const float4*>(X + (size_t)r * H);
        float acc = bj;
        #pragma unroll
        for (int k4 = 0; k4 < H / 4; ++k4) {
            float4 xv = xr[k4];
            if (RELU_IN) {
                xv.x = fmaxf(xv.x, 0.0f); xv.y = fmaxf(xv.y, 0.0f);
                xv.z = fmaxf(xv.z, 0.0f); xv.w = fmaxf(xv.w, 0.0f);
            }
            const int k = k4 * 4;
            acc = fmaf(xv.x, Ws[(k + 0) * H + j], acc);
            acc = fmaf(xv.y, Ws[(k + 1) * H + j], acc);
            acc = fmaf(xv.z, Ws[(k + 2) * H + j], acc);
            acc = fmaf(xv.w, Ws[(k + 3) * H + j], acc);
        }
        Y[(size_t)r * H + j] = acc;
    }
}

// ---------------------------------------------------------------------------
// Self-loop init: out[i][:] = h[i][:] * dis[i]^2   (also initializes out buffer)
__global__ void scatter_init(const float* __restrict__ h, const float* __restrict__ dis,
                             float* __restrict__ out) {
    int gid = blockIdx.x * blockDim.x + threadIdx.x;   // N*32 threads
    int i = gid >> 5;
    int c = gid & 31;
    float d = dis[i];
    float nm = d * d;
    float4 v = reinterpret_cast<const float4*>(h)[(size_t)i * 32 + c];
    v.x *= nm; v.y *= nm; v.z *= nm; v.w *= nm;
    reinterpret_cast<float4*>(out)[(size_t)i * 32 + c] = v;
}

// Edge scatter: out[col[e]][:] += h[row[e]][:] * norm[e]   (atomic f32)
__global__ void scatter_edges(const float* __restrict__ h, const int* __restrict__ row,
                              const int* __restrict__ col, const float* __restrict__ norm,
                              float* __restrict__ out) {
    unsigned gid = blockIdx.x * blockDim.x + threadIdx.x;  // E*32 threads
    int e = gid >> 5;
    int c = gid & 31;
    int r = row[e];
    int cc = col[e];
    float nm = norm[e];
    float4 v = reinterpret_cast<const float4*>(h)[(size_t)r * 32 + c];
    float* dst = out + (size_t)cc * H + c * 4;
    atomicAdd(dst + 0, v.x * nm);
    atomicAdd(dst + 1, v.y * nm);
    atomicAdd(dst + 2, v.z * nm);
    atomicAdd(dst + 3, v.w * nm);
}

// ---------------------------------------------------------------------------
// Fused global-mean-pool (with relu on input) + linear head.
// One block per graph; batch is sorted, so binary-search the bounds.
__global__ __launch_bounds__(128) void pool_linear(const float* __restrict__ h,
                                                   const int* __restrict__ batch,
                                                   const float* __restrict__ Wl,
                                                   const float* __restrict__ bl,
                                                   float* __restrict__ out) {
    const int g = blockIdx.x;
    const int j = threadIdx.x;
    __shared__ int bounds[2];
    if (j < 2) {
        int target = g + j;   // first index with batch[i] >= target
        int lo = 0, hi = N;
        while (lo < hi) {
            int mid = (lo + hi) >> 1;
            if (batch[mid] < target) lo = mid + 1; else hi = mid;
        }
        bounds[j] = lo;
    }
    __syncthreads();
    const int start = bounds[0], end = bounds[1];
    float acc = 0.0f;
    for (int i = start; i < end; ++i) acc += fmaxf(h[(size_t)i * H + j], 0.0f);
    float cnt = fmaxf((float)(end - start), 1.0f);
    float val = (acc / cnt) * Wl[j];
    __shared__ float red[128];
    red[j] = val;
    __syncthreads();
    #pragma unroll
    for (int s = 64; s > 0; s >>= 1) {
        if (j < s) red[j] += red[j + s];
        __syncthreads();
    }
    if (j == 0) out[g] = red[0] + bl[0];
}

// ---------------------------------------------------------------------------
extern "C" void kernel_launch(void* const* d_in, const int* in_sizes, int n_in,
                              void* d_out, int out_size, void* d_ws, size_t ws_size,
                              hipStream_t stream) {
    const float* x     = (const float*)d_in[0];
    const int*   ei    = (const int*)  d_in[1];   // [2, E] flat
    const int*   batch = (const int*)  d_in[2];
    // d_in[3] = dropout_rate (identity in eval mode) — ignored
    const float* W1 = (const float*)d_in[4];
    const float* b1 = (const float*)d_in[5];
    const float* W2 = (const float*)d_in[6];
    const float* b2 = (const float*)d_in[7];
    const float* W3 = (const float*)d_in[8];
    const float* b3 = (const float*)d_in[9];
    const float* Wl = (const float*)d_in[10];
    const float* bl = (const float*)d_in[11];
    float* out = (float*)d_out;

    const int* row = ei;       // source
    const int* col = ei + E;   // target

    // workspace layout (256B aligned)
    auto align256 = [](size_t v) { return (v + 255) & ~(size_t)255; };
    char* ws = (char*)d_ws;
    size_t off = 0;
    float* dis  = (float*)(ws + off); off += align256((size_t)N * 4);
    float* norm = (float*)(ws + off); off += align256((size_t)E * 4);
    float* bufA = (float*)(ws + off); off += align256((size_t)N * H * 4);
    float* bufB = (float*)(ws + off); off += align256((size_t)N * H * 4);
    (void)ws_size; (void)n_in; (void)in_sizes; (void)out_size;

    // --- norm precompute ---
    zero_f32<<<(N + 255) / 256, 256, 0, stream>>>(dis, N);
    count_deg<<<(E + 255) / 256, 256, 0, stream>>>(col, dis);
    finalize_dis<<<(N + 255) / 256, 256, 0, stream>>>(dis);
    compute_norm<<<(E + 255) / 256, 256, 0, stream>>>(row, col, dis, norm);

    const int gemm_grid    = N / 32;            // 1250
    const int init_grid    = (N * 32) / 256;    // 5000
    const int scatter_grid = (E * 32) / 256;    // 80000

    // --- layer 1 ---
    gemm_bias<false><<<gemm_grid, 256, 0, stream>>>(x, W1, b1, bufA);
    scatter_init<<<init_grid, 256, 0, stream>>>(bufA, dis, bufB);
    scatter_edges<<<scatter_grid, 256, 0, stream>>>(bufA, row, col, norm, bufB);
    // --- layer 2 ---
    gemm_bias<true><<<gemm_grid, 256, 0, stream>>>(bufB, W2, b2, bufA);
    scatter_init<<<init_grid, 256, 0, stream>>>(bufA, dis, bufB);
    scatter_edges<<<scatter_grid, 256, 0, stream>>>(bufA, row, col, norm, bufB);
    // --- layer 3 ---
    gemm_bias<true><<<gemm_grid, 256, 0, stream>>>(bufB, W3, b3, bufA);
    scatter_init<<<init_grid, 256, 0, stream>>>(bufA, dis, bufB);
    scatter_edges<<<scatter_grid, 256, 0, stream>>>(bufA, row, col, norm, bufB);
    // --- pool + head ---
    pool_linear<<<G, 128, 0, stream>>>(bufB, batch, Wl, bl, out);
}

// Round 2
// 722.217 us; speedup vs baseline: 5.4742x; 5.4742x over previous
//
#include <hip/hip_runtime.h>

// Problem constants (fixed by the reference's setup_inputs)
constexpr int N = 40000;    // nodes
constexpr int E = 640000;   // edges
constexpr int G = 64;       // graphs
constexpr int H = 128;      // hidden = F_IN

constexpr int NB = (N + 255) / 256;   // 157 blocks over nodes

// ---------------------------------------------------------------------------
__global__ void zero_int(int* __restrict__ p, int n) {
    int i = blockIdx.x * blockDim.x + threadIdx.x;
    if (i < n) p[i] = 0;
}

// deg[col[e]] += 1 for each edge (self-loop +1 added in finalize)
__global__ void count_deg(const int* __restrict__ col, int* __restrict__ deg) {
    int e = blockIdx.x * blockDim.x + threadIdx.x;
    if (e < E) atomicAdd(&deg[col[e]], 1);
}

// dis[i] = rsqrt(deg[i] + 1)
__global__ void finalize_dis(const int* __restrict__ deg, float* __restrict__ dis) {
    int i = blockIdx.x * blockDim.x + threadIdx.x;
    if (i < N) dis[i] = rsqrtf((float)(deg[i] + 1));
}

// per-block sums of deg for the scan
__global__ void block_sum(const int* __restrict__ deg, int* __restrict__ part) {
    __shared__ int s[256];
    int i = blockIdx.x * 256 + threadIdx.x;
    s[threadIdx.x] = (i < N) ? deg[i] : 0;
    __syncthreads();
    for (int off = 128; off > 0; off >>= 1) {
        if (threadIdx.x < off) s[threadIdx.x] += s[threadIdx.x + off];
        __syncthreads();
    }
    if (threadIdx.x == 0) part[blockIdx.x] = s[0];
}

// serial exclusive scan of the 157 partials (tiny)
__global__ void scan_part(int* __restrict__ part, int* __restrict__ row_ptr) {
    if (threadIdx.x == 0 && blockIdx.x == 0) {
        int run = 0;
        for (int b = 0; b < NB; ++b) { int t = part[b]; part[b] = run; run += t; }
        row_ptr[N] = run;   // == E
    }
}

// block-level exclusive scan + partial offset -> row_ptr, cursor
__global__ void scan_write(const int* __restrict__ deg, const int* __restrict__ part,
                           int* __restrict__ row_ptr, int* __restrict__ cursor) {
    __shared__ int s[256];
    int i = blockIdx.x * 256 + threadIdx.x;
    int val = (i < N) ? deg[i] : 0;
    s[threadIdx.x] = val;
    __syncthreads();
    // Hillis-Steele inclusive scan
    for (int off = 1; off < 256; off <<= 1) {
        int t = (threadIdx.x >= off) ? s[threadIdx.x - off] : 0;
        __syncthreads();
        s[threadIdx.x] += t;
        __syncthreads();
    }
    if (i < N) {
        int excl = s[threadIdx.x] - val + part[blockIdx.x];
        row_ptr[i] = excl;
        cursor[i] = excl;
    }
}

// fill CSR: for each edge, place (src, norm) into its destination's segment
__global__ void fill_csr(const int* __restrict__ row, const int* __restrict__ col,
                         const float* __restrict__ dis, int* __restrict__ cursor,
                         int2* __restrict__ csr) {
    int e = blockIdx.x * blockDim.x + threadIdx.x;
    if (e >= E) return;
    int r = row[e], c = col[e];
    float w = dis[r] * dis[c];
    int p = atomicAdd(&cursor[c], 1);
    csr[p] = make_int2(r, __float_as_int(w));
}

// ---------------------------------------------------------------------------
// Y[r][j] = sum_k relu?(X[r][k]) * W[k][j] + b[j]
// 256 threads = 2 halves x 128 cols; each thread register-blocks 4 rows so
// every LDS read of Ws feeds 4 FMAs (4x less LDS traffic).
template <bool RELU_IN>
__global__ __launch_bounds__(256) void gemm_bias(const float* __restrict__ X,
                                                 const float* __restrict__ W,
                                                 const float* __restrict__ b,
                                                 float* __restrict__ Y) {
    __shared__ float Ws[H * H];   // 64 KB
    const int tid = threadIdx.x;
    #pragma unroll 8
    for (int i = 0; i < (H * H) / 256; ++i) Ws[tid + i * 256] = W[tid + i * 256];
    const int j  = tid & 127;
    const int rh = tid >> 7;   // 0 or 1
    const float bj = b[j];
    __syncthreads();

    const int base_row = blockIdx.x * 32 + rh * 16;
    for (int rr = 0; rr < 16; rr += 4) {
        const int r = base_row + rr;
        const float4* x0 = reinterpret_cast<const float4*>(X + (size_t)r * H);
        const float4* x1 = x0 + 32;
        const float4* x2 = x0 + 64;
        const float4* x3 = x0 + 96;
        float a0 = bj, a1 = bj, a2 = bj, a3 = bj;
        #pragma unroll 4
        for (int k4 = 0; k4 < 32; ++k4) {
            float4 v0 = x0[k4], v1 = x1[k4], v2 = x2[k4], v3 = x3[k4];
            if (RELU_IN) {
                v0.x=fmaxf(v0.x,0.f); v0.y=fmaxf(v0.y,0.f); v0.z=fmaxf(v0.z,0.f); v0.w=fmaxf(v0.w,0.f);
                v1.x=fmaxf(v1.x,0.f); v1.y=fmaxf(v1.y,0.f); v1.z=fmaxf(v1.z,0.f); v1.w=fmaxf(v1.w,0.f);
                v2.x=fmaxf(v2.x,0.f); v2.y=fmaxf(v2.y,0.f); v2.z=fmaxf(v2.z,0.f); v2.w=fmaxf(v2.w,0.f);
                v3.x=fmaxf(v3.x,0.f); v3.y=fmaxf(v3.y,0.f); v3.z=fmaxf(v3.z,0.f); v3.w=fmaxf(v3.w,0.f);
            }
            const int k = k4 * 4;
            float w;
            w = Ws[(k + 0) * H + j];
            a0 = fmaf(v0.x, w, a0); a1 = fmaf(v1.x, w, a1);
            a2 = fmaf(v2.x, w, a2); a3 = fmaf(v3.x, w, a3);
            w = Ws[(k + 1) * H + j];
            a0 = fmaf(v0.y, w, a0); a1 = fmaf(v1.y, w, a1);
            a2 = fmaf(v2.y, w, a2); a3 = fmaf(v3.y, w, a3);
            w = Ws[(k + 2) * H + j];
            a0 = fmaf(v0.z, w, a0); a1 = fmaf(v1.z, w, a1);
            a2 = fmaf(v2.z, w, a2); a3 = fmaf(v3.z, w, a3);
            w = Ws[(k + 3) * H + j];
            a0 = fmaf(v0.w, w, a0); a1 = fmaf(v1.w, w, a1);
            a2 = fmaf(v2.w, w, a2); a3 = fmaf(v3.w, w, a3);
        }
        Y[(size_t)(r + 0) * H + j] = a0;
        Y[(size_t)(r + 1) * H + j] = a1;
        Y[(size_t)(r + 2) * H + j] = a2;
        Y[(size_t)(r + 3) * H + j] = a3;
    }
}

// ---------------------------------------------------------------------------
// Gather aggregation: out[i] = h[i]*dis[i]^2 + sum_{e: col=i} h[src[e]]*w[e]
// 32 lanes per node, float4 accumulator per lane. No atomics.
__global__ __launch_bounds__(256) void aggregate(const float* __restrict__ h,
                                                 const int2* __restrict__ csr,
                                                 const int* __restrict__ row_ptr,
                                                 const float* __restrict__ dis,
                                                 float* __restrict__ out) {
    int gid = blockIdx.x * 256 + threadIdx.x;   // N*32 threads exactly
    int i = gid >> 5;
    int c = gid & 31;
    const float4* h4 = reinterpret_cast<const float4*>(h);
    float d = dis[i];
    float4 acc = h4[(size_t)i * 32 + c];
    float sl = d * d;
    acc.x *= sl; acc.y *= sl; acc.z *= sl; acc.w *= sl;
    int p  = row_ptr[i];
    int p1 = row_ptr[i + 1];
    for (; p + 2 <= p1; p += 2) {
        int2 e0 = csr[p];
        int2 e1 = csr[p + 1];
        float4 v0 = h4[(size_t)e0.x * 32 + c];
        float4 v1 = h4[(size_t)e1.x * 32 + c];
        float w0 = __int_as_float(e0.y);
        float w1 = __int_as_float(e1.y);
        acc.x = fmaf(v0.x, w0, acc.x); acc.y = fmaf(v0.y, w0, acc.y);
        acc.z = fmaf(v0.z, w0, acc.z); acc.w = fmaf(v0.w, w0, acc.w);
        acc.x = fmaf(v1.x, w1, acc.x); acc.y = fmaf(v1.y, w1, acc.y);
        acc.z = fmaf(v1.z, w1, acc.z); acc.w = fmaf(v1.w, w1, acc.w);
    }
    if (p < p1) {
        int2 e0 = csr[p];
        float4 v0 = h4[(size_t)e0.x * 32 + c];
        float w0 = __int_as_float(e0.y);
        acc.x = fmaf(v0.x, w0, acc.x); acc.y = fmaf(v0.y, w0, acc.y);
        acc.z = fmaf(v0.z, w0, acc.z); acc.w = fmaf(v0.w, w0, acc.w);
    }
    reinterpret_cast<float4*>(out)[(size_t)i * 32 + c] = acc;
}

// ---------------------------------------------------------------------------
// Fused global-mean-pool (relu on input) + linear head.
__global__ __launch_bounds__(128) void pool_linear(const float* __restrict__ h,
                                                   const int* __restrict__ batch,
                                                   const float* __restrict__ Wl,
                                                   const float* __restrict__ bl,
                                                   float* __restrict__ out) {
    const int g = blockIdx.x;
    const int j = threadIdx.x;
    __shared__ int bounds[2];
    if (j < 2) {
        int target = g + j;
        int lo = 0, hi = N;
        while (lo < hi) {
            int mid = (lo + hi) >> 1;
            if (batch[mid] < target) lo = mid + 1; else hi = mid;
        }
        bounds[j] = lo;
    }
    __syncthreads();
    const int start = bounds[0], end = bounds[1];
    float acc = 0.0f;
    for (int i = start; i < end; ++i) acc += fmaxf(h[(size_t)i * H + j], 0.0f);
    float cnt = fmaxf((float)(end - start), 1.0f);
    float val = (acc / cnt) * Wl[j];
    __shared__ float red[128];
    red[j] = val;
    __syncthreads();
    #pragma unroll
    for (int s = 64; s > 0; s >>= 1) {
        if (j < s) red[j] += red[j + s];
        __syncthreads();
    }
    if (j == 0) out[g] = red[0] + bl[0];
}

// ---------------------------------------------------------------------------
extern "C" void kernel_launch(void* const* d_in, const int* in_sizes, int n_in,
                              void* d_out, int out_size, void* d_ws, size_t ws_size,
                              hipStream_t stream) {
    const float* x     = (const float*)d_in[0];
    const int*   ei    = (const int*)  d_in[1];   // [2, E] flat
    const int*   batch = (const int*)  d_in[2];
    const float* W1 = (const float*)d_in[4];
    const float* b1 = (const float*)d_in[5];
    const float* W2 = (const float*)d_in[6];
    const float* b2 = (const float*)d_in[7];
    const float* W3 = (const float*)d_in[8];
    const float* b3 = (const float*)d_in[9];
    const float* Wl = (const float*)d_in[10];
    const float* bl = (const float*)d_in[11];
    float* out = (float*)d_out;

    const int* row = ei;       // source
    const int* col = ei + E;   // target

    // workspace layout (256B aligned); ~47 MB total
    auto align256 = [](size_t v) { return (v + 255) & ~(size_t)255; };
    char* ws = (char*)d_ws;
    size_t off = 0;
    int*   deg     = (int*)  (ws + off); off += align256((size_t)N * 4);
    float* dis     = (float*)(ws + off); off += align256((size_t)N * 4);
    int*   row_ptr = (int*)  (ws + off); off += align256((size_t)(N + 1) * 4);
    int*   cursor  = (int*)  (ws + off); off += align256((size_t)N * 4);
    int*   part    = (int*)  (ws + off); off += align256((size_t)NB * 4);
    int2*  csr     = (int2*) (ws + off); off += align256((size_t)E * 8);
    float* bufA    = (float*)(ws + off); off += align256((size_t)N * H * 4);
    float* bufB    = (float*)(ws + off); off += align256((size_t)N * H * 4);
    (void)ws_size; (void)n_in; (void)in_sizes; (void)out_size;

    // --- CSR + norm precompute ---
    zero_int<<<NB, 256, 0, stream>>>(deg, N);
    count_deg<<<(E + 255) / 256, 256, 0, stream>>>(col, deg);
    finalize_dis<<<NB, 256, 0, stream>>>(deg, dis);
    block_sum<<<NB, 256, 0, stream>>>(deg, part);
    scan_part<<<1, 64, 0, stream>>>(part, row_ptr);
    scan_write<<<NB, 256, 0, stream>>>(deg, part, row_ptr, cursor);
    fill_csr<<<(E + 255) / 256, 256, 0, stream>>>(row, col, dis, cursor, csr);

    const int gemm_grid = N / 32;           // 1250
    const int agg_grid  = (N * 32) / 256;   // 5000

    // --- layer 1 ---
    gemm_bias<false><<<gemm_grid, 256, 0, stream>>>(x, W1, b1, bufA);
    aggregate<<<agg_grid, 256, 0, stream>>>(bufA, csr, row_ptr, dis, bufB);
    // --- layer 2 ---
    gemm_bias<true><<<gemm_grid, 256, 0, stream>>>(bufB, W2, b2, bufA);
    aggregate<<<agg_grid, 256, 0, stream>>>(bufA, csr, row_ptr, dis, bufB);
    // --- layer 3 ---
    gemm_bias<true><<<gemm_grid, 256, 0, stream>>>(bufB, W3, b3, bufA);
    aggregate<<<agg_grid, 256, 0, stream>>>(bufA, csr, row_ptr, dis, bufB);
    // --- pool + head ---
    pool_linear<<<G, 128, 0, stream>>>(bufB, batch, Wl, bl, out);
}

// Round 3
// 595.892 us; speedup vs baseline: 6.6347x; 1.2120x over previous
//
#include <hip/hip_runtime.h>

// Problem constants (fixed by the reference's setup_inputs)
constexpr int N = 40000;    // nodes
constexpr int E = 640000;   // edges
constexpr int G = 64;       // graphs
constexpr int H = 128;      // hidden = F_IN

constexpr int NB = (N + 255) / 256;   // 157 blocks over nodes

// ---------------------------------------------------------------------------
__global__ void zero_int(int* __restrict__ p, int n) {
    int i = blockIdx.x * blockDim.x + threadIdx.x;
    if (i < n) p[i] = 0;
}

__global__ void zero_f32(float* __restrict__ p, int n) {
    int i = blockIdx.x * blockDim.x + threadIdx.x;
    if (i < n) p[i] = 0.0f;
}

// deg[col[e]] += 1 for each edge (self-loop +1 added in finalize)
__global__ void count_deg(const int* __restrict__ col, int* __restrict__ deg) {
    int e = blockIdx.x * blockDim.x + threadIdx.x;
    if (e < E) atomicAdd(&deg[col[e]], 1);
}

// dis[i] = rsqrt(deg[i] + 1)
__global__ void finalize_dis(const int* __restrict__ deg, float* __restrict__ dis) {
    int i = blockIdx.x * blockDim.x + threadIdx.x;
    if (i < N) dis[i] = rsqrtf((float)(deg[i] + 1));
}

// per-block sums of deg for the scan
__global__ void block_sum(const int* __restrict__ deg, int* __restrict__ part) {
    __shared__ int s[256];
    int i = blockIdx.x * 256 + threadIdx.x;
    s[threadIdx.x] = (i < N) ? deg[i] : 0;
    __syncthreads();
    for (int off = 128; off > 0; off >>= 1) {
        if (threadIdx.x < off) s[threadIdx.x] += s[threadIdx.x + off];
        __syncthreads();
    }
    if (threadIdx.x == 0) part[blockIdx.x] = s[0];
}

// serial exclusive scan of the 157 partials (tiny)
__global__ void scan_part(int* __restrict__ part, int* __restrict__ row_ptr) {
    if (threadIdx.x == 0 && blockIdx.x == 0) {
        int run = 0;
        for (int b = 0; b < NB; ++b) { int t = part[b]; part[b] = run; run += t; }
        row_ptr[N] = run;   // == E
    }
}

// block-level exclusive scan + partial offset -> row_ptr, cursor
__global__ void scan_write(const int* __restrict__ deg, const int* __restrict__ part,
                           int* __restrict__ row_ptr, int* __restrict__ cursor) {
    __shared__ int s[256];
    int i = blockIdx.x * 256 + threadIdx.x;
    int val = (i < N) ? deg[i] : 0;
    s[threadIdx.x] = val;
    __syncthreads();
    // Hillis-Steele inclusive scan
    for (int off = 1; off < 256; off <<= 1) {
        int t = (threadIdx.x >= off) ? s[threadIdx.x - off] : 0;
        __syncthreads();
        s[threadIdx.x] += t;
        __syncthreads();
    }
    if (i < N) {
        int excl = s[threadIdx.x] - val + part[blockIdx.x];
        row_ptr[i] = excl;
        cursor[i] = excl;
    }
}

// fill CSR: for each edge, place (src, norm) into its destination's segment
__global__ void fill_csr(const int* __restrict__ row, const int* __restrict__ col,
                         const float* __restrict__ dis, int* __restrict__ cursor,
                         int2* __restrict__ csr) {
    int e = blockIdx.x * blockDim.x + threadIdx.x;
    if (e >= E) return;
    int r = row[e], c = col[e];
    float w = dis[r] * dis[c];
    int p = atomicAdd(&cursor[c], 1);
    csr[p] = make_int2(r, __float_as_int(w));
}

// ---------------------------------------------------------------------------
// Y[r][j] = sum_k relu?(X[r][k]) * W[k][j] + b[j]
// 256 threads = 2 halves x 128 cols; each thread register-blocks 4 rows so
// every LDS read of Ws feeds 4 FMAs.
template <bool RELU_IN>
__global__ __launch_bounds__(256) void gemm_bias(const float* __restrict__ X,
                                                 const float* __restrict__ W,
                                                 const float* __restrict__ b,
                                                 float* __restrict__ Y) {
    __shared__ float Ws[H * H];   // 64 KB
    const int tid = threadIdx.x;
    #pragma unroll 8
    for (int i = 0; i < (H * H) / 256; ++i) Ws[tid + i * 256] = W[tid + i * 256];
    const int j  = tid & 127;
    const int rh = tid >> 7;   // 0 or 1
    const float bj = b[j];
    __syncthreads();

    const int base_row = blockIdx.x * 32 + rh * 16;
    for (int rr = 0; rr < 16; rr += 4) {
        const int r = base_row + rr;
        const float4* x0 = reinterpret_cast<const float4*>(X + (size_t)r * H);
        const float4* x1 = x0 + 32;
        const float4* x2 = x0 + 64;
        const float4* x3 = x0 + 96;
        float a0 = bj, a1 = bj, a2 = bj, a3 = bj;
        #pragma unroll 4
        for (int k4 = 0; k4 < 32; ++k4) {
            float4 v0 = x0[k4], v1 = x1[k4], v2 = x2[k4], v3 = x3[k4];
            if (RELU_IN) {
                v0.x=fmaxf(v0.x,0.f); v0.y=fmaxf(v0.y,0.f); v0.z=fmaxf(v0.z,0.f); v0.w=fmaxf(v0.w,0.f);
                v1.x=fmaxf(v1.x,0.f); v1.y=fmaxf(v1.y,0.f); v1.z=fmaxf(v1.z,0.f); v1.w=fmaxf(v1.w,0.f);
                v2.x=fmaxf(v2.x,0.f); v2.y=fmaxf(v2.y,0.f); v2.z=fmaxf(v2.z,0.f); v2.w=fmaxf(v2.w,0.f);
                v3.x=fmaxf(v3.x,0.f); v3.y=fmaxf(v3.y,0.f); v3.z=fmaxf(v3.z,0.f); v3.w=fmaxf(v3.w,0.f);
            }
            const int k = k4 * 4;
            float w;
            w = Ws[(k + 0) * H + j];
            a0 = fmaf(v0.x, w, a0); a1 = fmaf(v1.x, w, a1);
            a2 = fmaf(v2.x, w, a2); a3 = fmaf(v3.x, w, a3);
            w = Ws[(k + 1) * H + j];
            a0 = fmaf(v0.y, w, a0); a1 = fmaf(v1.y, w, a1);
            a2 = fmaf(v2.y, w, a2); a3 = fmaf(v3.y, w, a3);
            w = Ws[(k + 2) * H + j];
            a0 = fmaf(v0.z, w, a0); a1 = fmaf(v1.z, w, a1);
            a2 = fmaf(v2.z, w, a2); a3 = fmaf(v3.z, w, a3);
            w = Ws[(k + 3) * H + j];
            a0 = fmaf(v0.w, w, a0); a1 = fmaf(v1.w, w, a1);
            a2 = fmaf(v2.w, w, a2); a3 = fmaf(v3.w, w, a3);
        }
        Y[(size_t)(r + 0) * H + j] = a0;
        Y[(size_t)(r + 1) * H + j] = a1;
        Y[(size_t)(r + 2) * H + j] = a2;
        Y[(size_t)(r + 3) * H + j] = a3;
    }
}

// ---------------------------------------------------------------------------
// Gather aggregation: out[i] = h[i]*dis[i]^2 + sum_{e: col=i} h[src[e]]*w[e]
// 32 lanes per node, float4 accumulator per lane. No atomics.
__global__ __launch_bounds__(256) void aggregate(const float* __restrict__ h,
                                                 const int2* __restrict__ csr,
                                                 const int* __restrict__ row_ptr,
                                                 const float* __restrict__ dis,
                                                 float* __restrict__ out) {
    int gid = blockIdx.x * 256 + threadIdx.x;   // N*32 threads exactly
    int i = gid >> 5;
    int c = gid & 31;
    const float4* h4 = reinterpret_cast<const float4*>(h);
    float d = dis[i];
    float4 acc = h4[(size_t)i * 32 + c];
    float sl = d * d;
    acc.x *= sl; acc.y *= sl; acc.z *= sl; acc.w *= sl;
    int p  = row_ptr[i];
    int p1 = row_ptr[i + 1];
    for (; p + 2 <= p1; p += 2) {
        int2 e0 = csr[p];
        int2 e1 = csr[p + 1];
        float4 v0 = h4[(size_t)e0.x * 32 + c];
        float4 v1 = h4[(size_t)e1.x * 32 + c];
        float w0 = __int_as_float(e0.y);
        float w1 = __int_as_float(e1.y);
        acc.x = fmaf(v0.x, w0, acc.x); acc.y = fmaf(v0.y, w0, acc.y);
        acc.z = fmaf(v0.z, w0, acc.z); acc.w = fmaf(v0.w, w0, acc.w);
        acc.x = fmaf(v1.x, w1, acc.x); acc.y = fmaf(v1.y, w1, acc.y);
        acc.z = fmaf(v1.z, w1, acc.z); acc.w = fmaf(v1.w, w1, acc.w);
    }
    if (p < p1) {
        int2 e0 = csr[p];
        float4 v0 = h4[(size_t)e0.x * 32 + c];
        float w0 = __int_as_float(e0.y);
        acc.x = fmaf(v0.x, w0, acc.x); acc.y = fmaf(v0.y, w0, acc.y);
        acc.z = fmaf(v0.z, w0, acc.z); acc.w = fmaf(v0.w, w0, acc.w);
    }
    reinterpret_cast<float4*>(out)[(size_t)i * 32 + c] = acc;
}

// ---------------------------------------------------------------------------
// Parallel mean-pool stage 1: each block streams a contiguous 128-node chunk,
// thread j accumulates relu(h[i][j]) into a running sum, flushing to
// pooled[g][j] (atomicAdd) when the graph id changes. batch is sorted, so
// flushes are rare (~1-2 per block).
constexpr int PCHUNK  = 128;
constexpr int PBLOCKS = (N + PCHUNK - 1) / PCHUNK;   // 313

__global__ __launch_bounds__(128) void pool_partial(const float* __restrict__ h,
                                                    const int* __restrict__ batch,
                                                    float* __restrict__ pooled) {
    const int start = blockIdx.x * PCHUNK;
    const int end   = min(start + PCHUNK, N);
    const int j = threadIdx.x;
    int cur = batch[start];
    float acc = 0.0f;
    for (int i = start; i < end; ++i) {
        int g = batch[i];                 // block-uniform
        if (g != cur) {
            atomicAdd(&pooled[cur * H + j], acc);
            acc = 0.0f;
            cur = g;
        }
        acc += fmaxf(h[(size_t)i * H + j], 0.0f);
    }
    atomicAdd(&pooled[cur * H + j], acc);
}

// Stage 2: out[g] = (pooled[g]/cnt[g]) . Wl + bl ; cnt via binary search.
__global__ __launch_bounds__(128) void head(const float* __restrict__ pooled,
                                            const int* __restrict__ batch,
                                            const float* __restrict__ Wl,
                                            const float* __restrict__ bl,
                                            float* __restrict__ out) {
    const int g = blockIdx.x;
    const int j = threadIdx.x;
    __shared__ int bounds[2];
    if (j < 2) {
        int target = g + j;
        int lo = 0, hi = N;
        while (lo < hi) {
            int mid = (lo + hi) >> 1;
            if (batch[mid] < target) lo = mid + 1; else hi = mid;
        }
        bounds[j] = lo;
    }
    __syncthreads();
    float cnt = fmaxf((float)(bounds[1] - bounds[0]), 1.0f);
    float val = (pooled[g * H + j] / cnt) * Wl[j];
    __shared__ float red[128];
    red[j] = val;
    __syncthreads();
    #pragma unroll
    for (int s = 64; s > 0; s >>= 1) {
        if (j < s) red[j] += red[j + s];
        __syncthreads();
    }
    if (j == 0) out[g] = red[0] + bl[0];
}

// ---------------------------------------------------------------------------
extern "C" void kernel_launch(void* const* d_in, const int* in_sizes, int n_in,
                              void* d_out, int out_size, void* d_ws, size_t ws_size,
                              hipStream_t stream) {
    const float* x     = (const float*)d_in[0];
    const int*   ei    = (const int*)  d_in[1];   // [2, E] flat
    const int*   batch = (const int*)  d_in[2];
    const float* W1 = (const float*)d_in[4];
    const float* b1 = (const float*)d_in[5];
    const float* W2 = (const float*)d_in[6];
    const float* b2 = (const float*)d_in[7];
    const float* W3 = (const float*)d_in[8];
    const float* b3 = (const float*)d_in[9];
    const float* Wl = (const float*)d_in[10];
    const float* bl = (const float*)d_in[11];
    float* out = (float*)d_out;

    const int* row = ei;       // source
    const int* col = ei + E;   // target

    // workspace layout (256B aligned); ~47 MB total
    auto align256 = [](size_t v) { return (v + 255) & ~(size_t)255; };
    char* ws = (char*)d_ws;
    size_t off = 0;
    int*   deg     = (int*)  (ws + off); off += align256((size_t)N * 4);
    float* dis     = (float*)(ws + off); off += align256((size_t)N * 4);
    int*   row_ptr = (int*)  (ws + off); off += align256((size_t)(N + 1) * 4);
    int*   cursor  = (int*)  (ws + off); off += align256((size_t)N * 4);
    int*   part    = (int*)  (ws + off); off += align256((size_t)NB * 4);
    int2*  csr     = (int2*) (ws + off); off += align256((size_t)E * 8);
    float* bufA    = (float*)(ws + off); off += align256((size_t)N * H * 4);
    float* bufB    = (float*)(ws + off); off += align256((size_t)N * H * 4);
    float* pooled  = (float*)(ws + off); off += align256((size_t)G * H * 4);
    (void)ws_size; (void)n_in; (void)in_sizes; (void)out_size;

    // --- CSR + norm precompute ---
    zero_int<<<NB, 256, 0, stream>>>(deg, N);
    count_deg<<<(E + 255) / 256, 256, 0, stream>>>(col, deg);
    finalize_dis<<<NB, 256, 0, stream>>>(deg, dis);
    block_sum<<<NB, 256, 0, stream>>>(deg, part);
    scan_part<<<1, 64, 0, stream>>>(part, row_ptr);
    scan_write<<<NB, 256, 0, stream>>>(deg, part, row_ptr, cursor);
    fill_csr<<<(E + 255) / 256, 256, 0, stream>>>(row, col, dis, cursor, csr);

    const int gemm_grid = N / 32;           // 1250
    const int agg_grid  = (N * 32) / 256;   // 5000

    // --- layer 1 ---
    gemm_bias<false><<<gemm_grid, 256, 0, stream>>>(x, W1, b1, bufA);
    aggregate<<<agg_grid, 256, 0, stream>>>(bufA, csr, row_ptr, dis, bufB);
    // --- layer 2 ---
    gemm_bias<true><<<gemm_grid, 256, 0, stream>>>(bufB, W2, b2, bufA);
    aggregate<<<agg_grid, 256, 0, stream>>>(bufA, csr, row_ptr, dis, bufB);
    // --- layer 3 ---
    gemm_bias<true><<<gemm_grid, 256, 0, stream>>>(bufB, W3, b3, bufA);
    aggregate<<<agg_grid, 256, 0, stream>>>(bufA, csr, row_ptr, dis, bufB);
    // --- pool + head ---
    zero_f32<<<(G * H + 255) / 256, 256, 0, stream>>>(pooled, G * H);
    pool_partial<<<PBLOCKS, 128, 0, stream>>>(bufB, batch, pooled);
    head<<<G, 128, 0, stream>>>(pooled, batch, Wl, bl, out);
}

// Round 4
// 436.896 us; speedup vs baseline: 9.0492x; 1.3639x over previous
//
#include <hip/hip_runtime.h>

// Problem constants (fixed by the reference's setup_inputs)
constexpr int N = 40000;    // nodes
constexpr int E = 640000;   // edges
constexpr int G = 64;       // graphs
constexpr int H = 128;      // hidden = F_IN

constexpr int NB = (N + 255) / 256;   // 157 blocks over nodes

// ---------------------------------------------------------------------------
__global__ void zero_int(int* __restrict__ p, int n) {
    int i = blockIdx.x * blockDim.x + threadIdx.x;
    if (i < n) p[i] = 0;
}

__global__ void zero_f32(float* __restrict__ p, int n) {
    int i = blockIdx.x * blockDim.x + threadIdx.x;
    if (i < n) p[i] = 0.0f;
}

// deg[col[e]] += 1 for each edge (self-loop +1 added in finalize)
__global__ void count_deg(const int* __restrict__ col, int* __restrict__ deg) {
    int e = blockIdx.x * blockDim.x + threadIdx.x;
    if (e < E) atomicAdd(&deg[col[e]], 1);
}

// dis[i] = rsqrt(deg[i] + 1)
__global__ void finalize_dis(const int* __restrict__ deg, float* __restrict__ dis) {
    int i = blockIdx.x * blockDim.x + threadIdx.x;
    if (i < N) dis[i] = rsqrtf((float)(deg[i] + 1));
}

// per-block sums of deg for the scan
__global__ void block_sum(const int* __restrict__ deg, int* __restrict__ part) {
    __shared__ int s[256];
    int i = blockIdx.x * 256 + threadIdx.x;
    s[threadIdx.x] = (i < N) ? deg[i] : 0;
    __syncthreads();
    for (int off = 128; off > 0; off >>= 1) {
        if (threadIdx.x < off) s[threadIdx.x] += s[threadIdx.x + off];
        __syncthreads();
    }
    if (threadIdx.x == 0) part[blockIdx.x] = s[0];
}

// serial exclusive scan of the 157 partials (tiny)
__global__ void scan_part(int* __restrict__ part, int* __restrict__ row_ptr) {
    if (threadIdx.x == 0 && blockIdx.x == 0) {
        int run = 0;
        for (int b = 0; b < NB; ++b) { int t = part[b]; part[b] = run; run += t; }
        row_ptr[N] = run;   // == E
    }
}

// block-level exclusive scan + partial offset -> row_ptr, cursor
__global__ void scan_write(const int* __restrict__ deg, const int* __restrict__ part,
                           int* __restrict__ row_ptr, int* __restrict__ cursor) {
    __shared__ int s[256];
    int i = blockIdx.x * 256 + threadIdx.x;
    int val = (i < N) ? deg[i] : 0;
    s[threadIdx.x] = val;
    __syncthreads();
    for (int off = 1; off < 256; off <<= 1) {
        int t = (threadIdx.x >= off) ? s[threadIdx.x - off] : 0;
        __syncthreads();
        s[threadIdx.x] += t;
        __syncthreads();
    }
    if (i < N) {
        int excl = s[threadIdx.x] - val + part[blockIdx.x];
        row_ptr[i] = excl;
        cursor[i] = excl;
    }
}

// fill CSR: for each edge, place (src, norm) into its destination's segment
__global__ void fill_csr(const int* __restrict__ row, const int* __restrict__ col,
                         const float* __restrict__ dis, int* __restrict__ cursor,
                         int2* __restrict__ csr) {
    int e = blockIdx.x * blockDim.x + threadIdx.x;
    if (e >= E) return;
    int r = row[e], c = col[e];
    float w = dis[r] * dis[c];
    int p = atomicAdd(&cursor[c], 1);
    csr[p] = make_int2(r, __float_as_int(w));
}

// ---------------------------------------------------------------------------
// Y[r][j] = sum_k relu?(X[r][k]) * W[k][j] + b[j]
// 256 threads: tid&31 = col-group (4 consecutive cols -> ds_read_b128 of W),
// tid>>5 = row-slot (4 consecutive rows). 4x4 register micro-tile: each
// ds_read_b128 feeds 16 FMAs. W staged in 2 halves of 32 KB so LDS/block
// stays at 32 KB (5 blocks/CU vs 2 with a 64 KB stage).
template <bool RELU_IN>
__global__ __launch_bounds__(256) void gemm_bias(const float* __restrict__ X,
                                                 const float* __restrict__ W,
                                                 const float* __restrict__ b,
                                                 float* __restrict__ Y) {
    __shared__ float4 Ws4[64 * 32];   // 32 KB: 64 k-rows x 128 cols
    const int tid = threadIdx.x;
    const int jg = tid & 31;    // col group: cols 4*jg .. 4*jg+3
    const int rs = tid >> 5;    // row slot: 8 slots x 4 rows
    const int r0 = blockIdx.x * 32 + rs * 4;

    const float4* W4 = reinterpret_cast<const float4*>(W);
    const float4* X4 = reinterpret_cast<const float4*>(X);

    const float4 bv = reinterpret_cast<const float4*>(b)[jg];
    float4 acc0 = bv, acc1 = bv, acc2 = bv, acc3 = bv;

    for (int half = 0; half < 2; ++half) {
        // stage W[half*64 .. +63][:] -> 2048 float4, 8 per thread
        #pragma unroll
        for (int i = 0; i < 8; ++i)
            Ws4[tid + i * 256] = W4[half * 2048 + tid + i * 256];
        __syncthreads();

        #pragma unroll 4
        for (int k4 = 0; k4 < 16; ++k4) {
            // x[r0..r0+3][4k .. 4k+3] (k offset by half*64)
            float4 xv0 = X4[(size_t)(r0 + 0) * 32 + half * 16 + k4];
            float4 xv1 = X4[(size_t)(r0 + 1) * 32 + half * 16 + k4];
            float4 xv2 = X4[(size_t)(r0 + 2) * 32 + half * 16 + k4];
            float4 xv3 = X4[(size_t)(r0 + 3) * 32 + half * 16 + k4];
            if (RELU_IN) {
                xv0.x=fmaxf(xv0.x,0.f); xv0.y=fmaxf(xv0.y,0.f); xv0.z=fmaxf(xv0.z,0.f); xv0.w=fmaxf(xv0.w,0.f);
                xv1.x=fmaxf(xv1.x,0.f); xv1.y=fmaxf(xv1.y,0.f); xv1.z=fmaxf(xv1.z,0.f); xv1.w=fmaxf(xv1.w,0.f);
                xv2.x=fmaxf(xv2.x,0.f); xv2.y=fmaxf(xv2.y,0.f); xv2.z=fmaxf(xv2.z,0.f); xv2.w=fmaxf(xv2.w,0.f);
                xv3.x=fmaxf(xv3.x,0.f); xv3.y=fmaxf(xv3.y,0.f); xv3.z=fmaxf(xv3.z,0.f); xv3.w=fmaxf(xv3.w,0.f);
            }
            #pragma unroll
            for (int kk = 0; kk < 4; ++kk) {
                float4 wv = Ws4[(k4 * 4 + kk) * 32 + jg];
                float xs0 = (kk==0)?xv0.x:(kk==1)?xv0.y:(kk==2)?xv0.z:xv0.w;
                float xs1 = (kk==0)?xv1.x:(kk==1)?xv1.y:(kk==2)?xv1.z:xv1.w;
                float xs2 = (kk==0)?xv2.x:(kk==1)?xv2.y:(kk==2)?xv2.z:xv2.w;
                float xs3 = (kk==0)?xv3.x:(kk==1)?xv3.y:(kk==2)?xv3.z:xv3.w;
                acc0.x = fmaf(xs0, wv.x, acc0.x); acc0.y = fmaf(xs0, wv.y, acc0.y);
                acc0.z = fmaf(xs0, wv.z, acc0.z); acc0.w = fmaf(xs0, wv.w, acc0.w);
                acc1.x = fmaf(xs1, wv.x, acc1.x); acc1.y = fmaf(xs1, wv.y, acc1.y);
                acc1.z = fmaf(xs1, wv.z, acc1.z); acc1.w = fmaf(xs1, wv.w, acc1.w);
                acc2.x = fmaf(xs2, wv.x, acc2.x); acc2.y = fmaf(xs2, wv.y, acc2.y);
                acc2.z = fmaf(xs2, wv.z, acc2.z); acc2.w = fmaf(xs2, wv.w, acc2.w);
                acc3.x = fmaf(xs3, wv.x, acc3.x); acc3.y = fmaf(xs3, wv.y, acc3.y);
                acc3.z = fmaf(xs3, wv.z, acc3.z); acc3.w = fmaf(xs3, wv.w, acc3.w);
            }
        }
        __syncthreads();   // before overwriting Ws4 with the next half
    }

    float4* Y4 = reinterpret_cast<float4*>(Y);
    Y4[(size_t)(r0 + 0) * 32 + jg] = acc0;
    Y4[(size_t)(r0 + 1) * 32 + jg] = acc1;
    Y4[(size_t)(r0 + 2) * 32 + jg] = acc2;
    Y4[(size_t)(r0 + 3) * 32 + jg] = acc3;
}

// ---------------------------------------------------------------------------
// Gather aggregation: out[i] = h[i]*dis[i]^2 + sum_{e: col=i} h[src[e]]*w[e]
__global__ __launch_bounds__(256) void aggregate(const float* __restrict__ h,
                                                 const int2* __restrict__ csr,
                                                 const int* __restrict__ row_ptr,
                                                 const float* __restrict__ dis,
                                                 float* __restrict__ out) {
    int gid = blockIdx.x * 256 + threadIdx.x;   // N*32 threads exactly
    int i = gid >> 5;
    int c = gid & 31;
    const float4* h4 = reinterpret_cast<const float4*>(h);
    float d = dis[i];
    float4 acc = h4[(size_t)i * 32 + c];
    float sl = d * d;
    acc.x *= sl; acc.y *= sl; acc.z *= sl; acc.w *= sl;
    int p  = row_ptr[i];
    int p1 = row_ptr[i + 1];
    for (; p + 2 <= p1; p += 2) {
        int2 e0 = csr[p];
        int2 e1 = csr[p + 1];
        float4 v0 = h4[(size_t)e0.x * 32 + c];
        float4 v1 = h4[(size_t)e1.x * 32 + c];
        float w0 = __int_as_float(e0.y);
        float w1 = __int_as_float(e1.y);
        acc.x = fmaf(v0.x, w0, acc.x); acc.y = fmaf(v0.y, w0, acc.y);
        acc.z = fmaf(v0.z, w0, acc.z); acc.w = fmaf(v0.w, w0, acc.w);
        acc.x = fmaf(v1.x, w1, acc.x); acc.y = fmaf(v1.y, w1, acc.y);
        acc.z = fmaf(v1.z, w1, acc.z); acc.w = fmaf(v1.w, w1, acc.w);
    }
    if (p < p1) {
        int2 e0 = csr[p];
        float4 v0 = h4[(size_t)e0.x * 32 + c];
        float w0 = __int_as_float(e0.y);
        acc.x = fmaf(v0.x, w0, acc.x); acc.y = fmaf(v0.y, w0, acc.y);
        acc.z = fmaf(v0.z, w0, acc.z); acc.w = fmaf(v0.w, w0, acc.w);
    }
    reinterpret_cast<float4*>(out)[(size_t)i * 32 + c] = acc;
}

// ---------------------------------------------------------------------------
// Parallel mean-pool stage 1 (see R3 notes): block streams a 128-node chunk,
// flush-on-graph-change atomicAdd into pooled[G][H].
constexpr int PCHUNK  = 128;
constexpr int PBLOCKS = (N + PCHUNK - 1) / PCHUNK;   // 313

__global__ __launch_bounds__(128) void pool_partial(const float* __restrict__ h,
                                                    const int* __restrict__ batch,
                                                    float* __restrict__ pooled) {
    const int start = blockIdx.x * PCHUNK;
    const int end   = min(start + PCHUNK, N);
    const int j = threadIdx.x;
    int cur = batch[start];
    float acc = 0.0f;
    for (int i = start; i < end; ++i) {
        int g = batch[i];                 // block-uniform
        if (g != cur) {
            atomicAdd(&pooled[cur * H + j], acc);
            acc = 0.0f;
            cur = g;
        }
        acc += fmaxf(h[(size_t)i * H + j], 0.0f);
    }
    atomicAdd(&pooled[cur * H + j], acc);
}

// Stage 2: out[g] = (pooled[g]/cnt[g]) . Wl + bl ; cnt via binary search.
__global__ __launch_bounds__(128) void head(const float* __restrict__ pooled,
                                            const int* __restrict__ batch,
                                            const float* __restrict__ Wl,
                                            const float* __restrict__ bl,
                                            float* __restrict__ out) {
    const int g = blockIdx.x;
    const int j = threadIdx.x;
    __shared__ int bounds[2];
    if (j < 2) {
        int target = g + j;
        int lo = 0, hi = N;
        while (lo < hi) {
            int mid = (lo + hi) >> 1;
            if (batch[mid] < target) lo = mid + 1; else hi = mid;
        }
        bounds[j] = lo;
    }
    __syncthreads();
    float cnt = fmaxf((float)(bounds[1] - bounds[0]), 1.0f);
    float val = (pooled[g * H + j] / cnt) * Wl[j];
    __shared__ float red[128];
    red[j] = val;
    __syncthreads();
    #pragma unroll
    for (int s = 64; s > 0; s >>= 1) {
        if (j < s) red[j] += red[j + s];
        __syncthreads();
    }
    if (j == 0) out[g] = red[0] + bl[0];
}

// ---------------------------------------------------------------------------
extern "C" void kernel_launch(void* const* d_in, const int* in_sizes, int n_in,
                              void* d_out, int out_size, void* d_ws, size_t ws_size,
                              hipStream_t stream) {
    const float* x     = (const float*)d_in[0];
    const int*   ei    = (const int*)  d_in[1];   // [2, E] flat
    const int*   batch = (const int*)  d_in[2];
    const float* W1 = (const float*)d_in[4];
    const float* b1 = (const float*)d_in[5];
    const float* W2 = (const float*)d_in[6];
    const float* b2 = (const float*)d_in[7];
    const float* W3 = (const float*)d_in[8];
    const float* b3 = (const float*)d_in[9];
    const float* Wl = (const float*)d_in[10];
    const float* bl = (const float*)d_in[11];
    float* out = (float*)d_out;

    const int* row = ei;       // source
    const int* col = ei + E;   // target

    // workspace layout (256B aligned); ~47 MB total
    auto align256 = [](size_t v) { return (v + 255) & ~(size_t)255; };
    char* ws = (char*)d_ws;
    size_t off = 0;
    int*   deg     = (int*)  (ws + off); off += align256((size_t)N * 4);
    float* dis     = (float*)(ws + off); off += align256((size_t)N * 4);
    int*   row_ptr = (int*)  (ws + off); off += align256((size_t)(N + 1) * 4);
    int*   cursor  = (int*)  (ws + off); off += align256((size_t)N * 4);
    int*   part    = (int*)  (ws + off); off += align256((size_t)NB * 4);
    int2*  csr     = (int2*) (ws + off); off += align256((size_t)E * 8);
    float* bufA    = (float*)(ws + off); off += align256((size_t)N * H * 4);
    float* bufB    = (float*)(ws + off); off += align256((size_t)N * H * 4);
    float* pooled  = (float*)(ws + off); off += align256((size_t)G * H * 4);
    (void)ws_size; (void)n_in; (void)in_sizes; (void)out_size;

    // --- CSR + norm precompute ---
    zero_int<<<NB, 256, 0, stream>>>(deg, N);
    count_deg<<<(E + 255) / 256, 256, 0, stream>>>(col, deg);
    finalize_dis<<<NB, 256, 0, stream>>>(deg, dis);
    block_sum<<<NB, 256, 0, stream>>>(deg, part);
    scan_part<<<1, 64, 0, stream>>>(part, row_ptr);
    scan_write<<<NB, 256, 0, stream>>>(deg, part, row_ptr, cursor);
    fill_csr<<<(E + 255) / 256, 256, 0, stream>>>(row, col, dis, cursor, csr);

    const int gemm_grid = N / 32;           // 1250
    const int agg_grid  = (N * 32) / 256;   // 5000

    // --- layer 1 ---
    gemm_bias<false><<<gemm_grid, 256, 0, stream>>>(x, W1, b1, bufA);
    aggregate<<<agg_grid, 256, 0, stream>>>(bufA, csr, row_ptr, dis, bufB);
    // --- layer 2 ---
    gemm_bias<true><<<gemm_grid, 256, 0, stream>>>(bufB, W2, b2, bufA);
    aggregate<<<agg_grid, 256, 0, stream>>>(bufA, csr, row_ptr, dis, bufB);
    // --- layer 3 ---
    gemm_bias<true><<<gemm_grid, 256, 0, stream>>>(bufB, W3, b3, bufA);
    aggregate<<<agg_grid, 256, 0, stream>>>(bufA, csr, row_ptr, dis, bufB);
    // --- pool + head ---
    zero_f32<<<(G * H + 255) / 256, 256, 0, stream>>>(pooled, G * H);
    pool_partial<<<PBLOCKS, 128, 0, stream>>>(bufB, batch, pooled);
    head<<<G, 128, 0, stream>>>(pooled, batch, Wl, bl, out);
}

// Round 5
// 396.853 us; speedup vs baseline: 9.9622x; 1.1009x over previous
//
#include <hip/hip_runtime.h>

// Problem constants (fixed by the reference's setup_inputs)
constexpr int N = 40000;    // nodes
constexpr int E = 640000;   // edges
constexpr int G = 64;       // graphs
constexpr int H = 128;      // hidden = F_IN

constexpr int NB = (N + 255) / 256;   // 157 blocks over nodes

// ---------------------------------------------------------------------------
__global__ void zero_int(int* __restrict__ p, int n) {
    int i = blockIdx.x * blockDim.x + threadIdx.x;
    if (i < n) p[i] = 0;
}

__global__ void zero_f32(float* __restrict__ p, int n) {
    int i = blockIdx.x * blockDim.x + threadIdx.x;
    if (i < n) p[i] = 0.0f;
}

// deg[col[e]] += 1 for each edge (self-loop +1 added in finalize)
__global__ void count_deg(const int* __restrict__ col, int* __restrict__ deg) {
    int e = blockIdx.x * blockDim.x + threadIdx.x;
    if (e < E) atomicAdd(&deg[col[e]], 1);
}

// dis[i] = rsqrt(deg[i] + 1)
__global__ void finalize_dis(const int* __restrict__ deg, float* __restrict__ dis) {
    int i = blockIdx.x * blockDim.x + threadIdx.x;
    if (i < N) dis[i] = rsqrtf((float)(deg[i] + 1));
}

// per-block sums of deg for the scan
__global__ void block_sum(const int* __restrict__ deg, int* __restrict__ part) {
    __shared__ int s[256];
    int i = blockIdx.x * 256 + threadIdx.x;
    s[threadIdx.x] = (i < N) ? deg[i] : 0;
    __syncthreads();
    for (int off = 128; off > 0; off >>= 1) {
        if (threadIdx.x < off) s[threadIdx.x] += s[threadIdx.x + off];
        __syncthreads();
    }
    if (threadIdx.x == 0) part[blockIdx.x] = s[0];
}

// serial exclusive scan of the 157 partials (tiny)
__global__ void scan_part(int* __restrict__ part, int* __restrict__ row_ptr) {
    if (threadIdx.x == 0 && blockIdx.x == 0) {
        int run = 0;
        for (int b = 0; b < NB; ++b) { int t = part[b]; part[b] = run; run += t; }
        row_ptr[N] = run;   // == E
    }
}

// block-level exclusive scan + partial offset -> row_ptr, cursor
__global__ void scan_write(const int* __restrict__ deg, const int* __restrict__ part,
                           int* __restrict__ row_ptr, int* __restrict__ cursor) {
    __shared__ int s[256];
    int i = blockIdx.x * 256 + threadIdx.x;
    int val = (i < N) ? deg[i] : 0;
    s[threadIdx.x] = val;
    __syncthreads();
    for (int off = 1; off < 256; off <<= 1) {
        int t = (threadIdx.x >= off) ? s[threadIdx.x - off] : 0;
        __syncthreads();
        s[threadIdx.x] += t;
        __syncthreads();
    }
    if (i < N) {
        int excl = s[threadIdx.x] - val + part[blockIdx.x];
        row_ptr[i] = excl;
        cursor[i] = excl;
    }
}

// fill CSR: for each edge, place (src, norm) into its destination's segment
__global__ void fill_csr(const int* __restrict__ row, const int* __restrict__ col,
                         const float* __restrict__ dis, int* __restrict__ cursor,
                         int2* __restrict__ csr) {
    int e = blockIdx.x * blockDim.x + threadIdx.x;
    if (e >= E) return;
    int r = row[e], c = col[e];
    float w = dis[r] * dis[c];
    int p = atomicAdd(&cursor[c], 1);
    csr[p] = make_int2(r, __float_as_int(w));
}

// ---------------------------------------------------------------------------
// Standalone GEMM (layer 1 only): Y = X.W + b, 4x4 register micro-tile,
// W staged in 2 x 32 KB halves.
__global__ __launch_bounds__(256) void gemm_bias(const float* __restrict__ X,
                                                 const float* __restrict__ W,
                                                 const float* __restrict__ b,
                                                 float* __restrict__ Y) {
    __shared__ float4 Ws4[64 * 32];   // 32 KB
    const int tid = threadIdx.x;
    const int jg = tid & 31;
    const int rs = tid >> 5;
    const int r0 = blockIdx.x * 32 + rs * 4;

    const float4* W4 = reinterpret_cast<const float4*>(W);
    const float4* X4 = reinterpret_cast<const float4*>(X);

    const float4 bv = reinterpret_cast<const float4*>(b)[jg];
    float4 acc0 = bv, acc1 = bv, acc2 = bv, acc3 = bv;

    for (int half = 0; half < 2; ++half) {
        #pragma unroll
        for (int i = 0; i < 8; ++i)
            Ws4[tid + i * 256] = W4[half * 2048 + tid + i * 256];
        __syncthreads();

        #pragma unroll 4
        for (int k4 = 0; k4 < 16; ++k4) {
            float4 xv0 = X4[(size_t)(r0 + 0) * 32 + half * 16 + k4];
            float4 xv1 = X4[(size_t)(r0 + 1) * 32 + half * 16 + k4];
            float4 xv2 = X4[(size_t)(r0 + 2) * 32 + half * 16 + k4];
            float4 xv3 = X4[(size_t)(r0 + 3) * 32 + half * 16 + k4];
            #pragma unroll
            for (int kk = 0; kk < 4; ++kk) {
                float4 wv = Ws4[(k4 * 4 + kk) * 32 + jg];
                float xs0 = (kk==0)?xv0.x:(kk==1)?xv0.y:(kk==2)?xv0.z:xv0.w;
                float xs1 = (kk==0)?xv1.x:(kk==1)?xv1.y:(kk==2)?xv1.z:xv1.w;
                float xs2 = (kk==0)?xv2.x:(kk==1)?xv2.y:(kk==2)?xv2.z:xv2.w;
                float xs3 = (kk==0)?xv3.x:(kk==1)?xv3.y:(kk==2)?xv3.z:xv3.w;
                acc0.x = fmaf(xs0, wv.x, acc0.x); acc0.y = fmaf(xs0, wv.y, acc0.y);
                acc0.z = fmaf(xs0, wv.z, acc0.z); acc0.w = fmaf(xs0, wv.w, acc0.w);
                acc1.x = fmaf(xs1, wv.x, acc1.x); acc1.y = fmaf(xs1, wv.y, acc1.y);
                acc1.z = fmaf(xs1, wv.z, acc1.z); acc1.w = fmaf(xs1, wv.w, acc1.w);
                acc2.x = fmaf(xs2, wv.x, acc2.x); acc2.y = fmaf(xs2, wv.y, acc2.y);
                acc2.z = fmaf(xs2, wv.z, acc2.z); acc2.w = fmaf(xs2, wv.w, acc2.w);
                acc3.x = fmaf(xs3, wv.x, acc3.x); acc3.y = fmaf(xs3, wv.y, acc3.y);
                acc3.z = fmaf(xs3, wv.z, acc3.z); acc3.w = fmaf(xs3, wv.w, acc3.w);
            }
        }
        __syncthreads();
    }

    float4* Y4 = reinterpret_cast<float4*>(Y);
    Y4[(size_t)(r0 + 0) * 32 + jg] = acc0;
    Y4[(size_t)(r0 + 1) * 32 + jg] = acc1;
    Y4[(size_t)(r0 + 2) * 32 + jg] = acc2;
    Y4[(size_t)(r0 + 3) * 32 + jg] = acc3;
}

// ---------------------------------------------------------------------------
// Fused layer: t_out = relu(agg(t_in)) . W + b
// Phase A: aggregate 32 nodes (4 sub-batches of 8; 32 lanes/node, float4
// accumulators) + relu -> LDS tile (16 KB).
// Phase B: tile . W with W staged in 4 x 16 KB quarters (LDS/block = 32 KB
// -> 5 blocks/CU, same occupancy as the standalone aggregate).
__global__ __launch_bounds__(256) void fused_agg_gemm(const float* __restrict__ t_in,
                                                      const int2* __restrict__ csr,
                                                      const int* __restrict__ row_ptr,
                                                      const float* __restrict__ dis,
                                                      const float* __restrict__ W,
                                                      const float* __restrict__ b,
                                                      float* __restrict__ t_out) {
    __shared__ float4 tile[32 * 32];  // 16 KB: 32 nodes x 128 feats
    __shared__ float4 Wq[32 * 32];    // 16 KB: 32 k-rows x 128 cols
    const int tid = threadIdx.x;
    const int node0 = blockIdx.x * 32;
    const float4* h4 = reinterpret_cast<const float4*>(t_in);

    {   // ---- Phase A: aggregate + relu ----
        const int c  = tid & 31;
        const int nl = tid >> 5;
        #pragma unroll
        for (int sub = 0; sub < 4; ++sub) {
            const int local = sub * 8 + nl;
            const int i = node0 + local;
            float d = dis[i];
            float sl = d * d;
            float4 acc = h4[(size_t)i * 32 + c];
            acc.x *= sl; acc.y *= sl; acc.z *= sl; acc.w *= sl;
            int p  = row_ptr[i];
            int p1 = row_ptr[i + 1];
            for (; p + 2 <= p1; p += 2) {
                int2 e0 = csr[p];
                int2 e1 = csr[p + 1];
                float4 v0 = h4[(size_t)e0.x * 32 + c];
                float4 v1 = h4[(size_t)e1.x * 32 + c];
                float w0 = __int_as_float(e0.y);
                float w1 = __int_as_float(e1.y);
                acc.x = fmaf(v0.x, w0, acc.x); acc.y = fmaf(v0.y, w0, acc.y);
                acc.z = fmaf(v0.z, w0, acc.z); acc.w = fmaf(v0.w, w0, acc.w);
                acc.x = fmaf(v1.x, w1, acc.x); acc.y = fmaf(v1.y, w1, acc.y);
                acc.z = fmaf(v1.z, w1, acc.z); acc.w = fmaf(v1.w, w1, acc.w);
            }
            if (p < p1) {
                int2 e0 = csr[p];
                float4 v0 = h4[(size_t)e0.x * 32 + c];
                float w0 = __int_as_float(e0.y);
                acc.x = fmaf(v0.x, w0, acc.x); acc.y = fmaf(v0.y, w0, acc.y);
                acc.z = fmaf(v0.z, w0, acc.z); acc.w = fmaf(v0.w, w0, acc.w);
            }
            acc.x = fmaxf(acc.x, 0.f); acc.y = fmaxf(acc.y, 0.f);
            acc.z = fmaxf(acc.z, 0.f); acc.w = fmaxf(acc.w, 0.f);
            tile[local * 32 + c] = acc;
        }
    }
    __syncthreads();

    // ---- Phase B: GEMM from LDS tile ----
    const int jg = tid & 31;
    const int rs = tid >> 5;
    const int r0 = rs * 4;   // local row base
    const float4* W4 = reinterpret_cast<const float4*>(W);
    const float4 bv = reinterpret_cast<const float4*>(b)[jg];
    float4 acc0 = bv, acc1 = bv, acc2 = bv, acc3 = bv;

    for (int q = 0; q < 4; ++q) {
        #pragma unroll
        for (int i2 = 0; i2 < 4; ++i2)
            Wq[tid + i2 * 256] = W4[q * 1024 + tid + i2 * 256];
        __syncthreads();

        #pragma unroll
        for (int k4 = 0; k4 < 8; ++k4) {
            float4 xv0 = tile[(r0 + 0) * 32 + q * 8 + k4];
            float4 xv1 = tile[(r0 + 1) * 32 + q * 8 + k4];
            float4 xv2 = tile[(r0 + 2) * 32 + q * 8 + k4];
            float4 xv3 = tile[(r0 + 3) * 32 + q * 8 + k4];
            #pragma unroll
            for (int kk = 0; kk < 4; ++kk) {
                float4 wv = Wq[(k4 * 4 + kk) * 32 + jg];
                float xs0 = (kk==0)?xv0.x:(kk==1)?xv0.y:(kk==2)?xv0.z:xv0.w;
                float xs1 = (kk==0)?xv1.x:(kk==1)?xv1.y:(kk==2)?xv1.z:xv1.w;
                float xs2 = (kk==0)?xv2.x:(kk==1)?xv2.y:(kk==2)?xv2.z:xv2.w;
                float xs3 = (kk==0)?xv3.x:(kk==1)?xv3.y:(kk==2)?xv3.z:xv3.w;
                acc0.x = fmaf(xs0, wv.x, acc0.x); acc0.y = fmaf(xs0, wv.y, acc0.y);
                acc0.z = fmaf(xs0, wv.z, acc0.z); acc0.w = fmaf(xs0, wv.w, acc0.w);
                acc1.x = fmaf(xs1, wv.x, acc1.x); acc1.y = fmaf(xs1, wv.y, acc1.y);
                acc1.z = fmaf(xs1, wv.z, acc1.z); acc1.w = fmaf(xs1, wv.w, acc1.w);
                acc2.x = fmaf(xs2, wv.x, acc2.x); acc2.y = fmaf(xs2, wv.y, acc2.y);
                acc2.z = fmaf(xs2, wv.z, acc2.z); acc2.w = fmaf(xs2, wv.w, acc2.w);
                acc3.x = fmaf(xs3, wv.x, acc3.x); acc3.y = fmaf(xs3, wv.y, acc3.y);
                acc3.z = fmaf(xs3, wv.z, acc3.z); acc3.w = fmaf(xs3, wv.w, acc3.w);
            }
        }
        __syncthreads();
    }

    float4* Y4 = reinterpret_cast<float4*>(t_out);
    const int gr0 = node0 + r0;
    Y4[(size_t)(gr0 + 0) * 32 + jg] = acc0;
    Y4[(size_t)(gr0 + 1) * 32 + jg] = acc1;
    Y4[(size_t)(gr0 + 2) * 32 + jg] = acc2;
    Y4[(size_t)(gr0 + 3) * 32 + jg] = acc3;
}

// ---------------------------------------------------------------------------
// Fused layer 3 tail: relu(agg(t_in)) accumulated straight into pooled[G][H]
// (run-flush atomics; batch sorted -> ~1 flush per block). h3 never hits HBM.
__global__ __launch_bounds__(256) void fused_agg_pool(const float* __restrict__ t_in,
                                                      const int2* __restrict__ csr,
                                                      const int* __restrict__ row_ptr,
                                                      const float* __restrict__ dis,
                                                      const int* __restrict__ batch,
                                                      float* __restrict__ pooled) {
    __shared__ float4 tile[8 * 32];   // 4 KB: 8 nodes x 128 feats
    const int tid = threadIdx.x;
    const int c  = tid & 31;
    const int nl = tid >> 5;
    const int i0 = blockIdx.x * 8;
    const int i = i0 + nl;
    const float4* h4 = reinterpret_cast<const float4*>(t_in);

    float d = dis[i];
    float sl = d * d;
    float4 acc = h4[(size_t)i * 32 + c];
    acc.x *= sl; acc.y *= sl; acc.z *= sl; acc.w *= sl;
    int p  = row_ptr[i];
    int p1 = row_ptr[i + 1];
    for (; p + 2 <= p1; p += 2) {
        int2 e0 = csr[p];
        int2 e1 = csr[p + 1];
        float4 v0 = h4[(size_t)e0.x * 32 + c];
        float4 v1 = h4[(size_t)e1.x * 32 + c];
        float w0 = __int_as_float(e0.y);
        float w1 = __int_as_float(e1.y);
        acc.x = fmaf(v0.x, w0, acc.x); acc.y = fmaf(v0.y, w0, acc.y);
        acc.z = fmaf(v0.z, w0, acc.z); acc.w = fmaf(v0.w, w0, acc.w);
        acc.x = fmaf(v1.x, w1, acc.x); acc.y = fmaf(v1.y, w1, acc.y);
        acc.z = fmaf(v1.z, w1, acc.z); acc.w = fmaf(v1.w, w1, acc.w);
    }
    if (p < p1) {
        int2 e0 = csr[p];
        float4 v0 = h4[(size_t)e0.x * 32 + c];
        float w0 = __int_as_float(e0.y);
        acc.x = fmaf(v0.x, w0, acc.x); acc.y = fmaf(v0.y, w0, acc.y);
        acc.z = fmaf(v0.z, w0, acc.z); acc.w = fmaf(v0.w, w0, acc.w);
    }
    acc.x = fmaxf(acc.x, 0.f); acc.y = fmaxf(acc.y, 0.f);
    acc.z = fmaxf(acc.z, 0.f); acc.w = fmaxf(acc.w, 0.f);
    tile[nl * 32 + c] = acc;
    __syncthreads();

    if (tid < 128) {
        const int j = tid;
        const float* tf = reinterpret_cast<const float*>(tile);
        int cur = batch[i0];
        float s = 0.0f;
        #pragma unroll
        for (int r = 0; r < 8; ++r) {
            int g = batch[i0 + r];
            if (g != cur) { atomicAdd(&pooled[cur * H + j], s); s = 0.0f; cur = g; }
            s += tf[r * 128 + j];
        }
        atomicAdd(&pooled[cur * H + j], s);
    }
}

// Head: out[g] = (pooled[g]/cnt[g]) . Wl + bl ; cnt via binary search.
__global__ __launch_bounds__(128) void head(const float* __restrict__ pooled,
                                            const int* __restrict__ batch,
                                            const float* __restrict__ Wl,
                                            const float* __restrict__ bl,
                                            float* __restrict__ out) {
    const int g = blockIdx.x;
    const int j = threadIdx.x;
    __shared__ int bounds[2];
    if (j < 2) {
        int target = g + j;
        int lo = 0, hi = N;
        while (lo < hi) {
            int mid = (lo + hi) >> 1;
            if (batch[mid] < target) lo = mid + 1; else hi = mid;
        }
        bounds[j] = lo;
    }
    __syncthreads();
    float cnt = fmaxf((float)(bounds[1] - bounds[0]), 1.0f);
    float val = (pooled[g * H + j] / cnt) * Wl[j];
    __shared__ float red[128];
    red[j] = val;
    __syncthreads();
    #pragma unroll
    for (int s = 64; s > 0; s >>= 1) {
        if (j < s) red[j] += red[j + s];
        __syncthreads();
    }
    if (j == 0) out[g] = red[0] + bl[0];
}

// ---------------------------------------------------------------------------
extern "C" void kernel_launch(void* const* d_in, const int* in_sizes, int n_in,
                              void* d_out, int out_size, void* d_ws, size_t ws_size,
                              hipStream_t stream) {
    const float* x     = (const float*)d_in[0];
    const int*   ei    = (const int*)  d_in[1];   // [2, E] flat
    const int*   batch = (const int*)  d_in[2];
    const float* W1 = (const float*)d_in[4];
    const float* b1 = (const float*)d_in[5];
    const float* W2 = (const float*)d_in[6];
    const float* b2 = (const float*)d_in[7];
    const float* W3 = (const float*)d_in[8];
    const float* b3 = (const float*)d_in[9];
    const float* Wl = (const float*)d_in[10];
    const float* bl = (const float*)d_in[11];
    float* out = (float*)d_out;

    const int* row = ei;       // source
    const int* col = ei + E;   // target

    // workspace layout (256B aligned); ~47 MB total
    auto align256 = [](size_t v) { return (v + 255) & ~(size_t)255; };
    char* ws = (char*)d_ws;
    size_t off = 0;
    int*   deg     = (int*)  (ws + off); off += align256((size_t)N * 4);
    float* dis     = (float*)(ws + off); off += align256((size_t)N * 4);
    int*   row_ptr = (int*)  (ws + off); off += align256((size_t)(N + 1) * 4);
    int*   cursor  = (int*)  (ws + off); off += align256((size_t)N * 4);
    int*   part    = (int*)  (ws + off); off += align256((size_t)NB * 4);
    int2*  csr     = (int2*) (ws + off); off += align256((size_t)E * 8);
    float* bufA    = (float*)(ws + off); off += align256((size_t)N * H * 4);
    float* bufB    = (float*)(ws + off); off += align256((size_t)N * H * 4);
    float* pooled  = (float*)(ws + off); off += align256((size_t)G * H * 4);
    (void)ws_size; (void)n_in; (void)in_sizes; (void)out_size;

    // --- CSR + norm precompute ---
    zero_int<<<NB, 256, 0, stream>>>(deg, N);
    count_deg<<<(E + 255) / 256, 256, 0, stream>>>(col, deg);
    finalize_dis<<<NB, 256, 0, stream>>>(deg, dis);
    block_sum<<<NB, 256, 0, stream>>>(deg, part);
    scan_part<<<1, 64, 0, stream>>>(part, row_ptr);
    scan_write<<<NB, 256, 0, stream>>>(deg, part, row_ptr, cursor);
    fill_csr<<<(E + 255) / 256, 256, 0, stream>>>(row, col, dis, cursor, csr);

    // pooled must be zero before fused_agg_pool accumulates
    zero_f32<<<(G * H + 255) / 256, 256, 0, stream>>>(pooled, G * H);

    const int gemm_grid  = N / 32;   // 1250
    const int fused_grid = N / 32;   // 1250
    const int agg3_grid  = N / 8;    // 5000

    // layer 1: t1 = x.W1 + b1
    gemm_bias<<<gemm_grid, 256, 0, stream>>>(x, W1, b1, bufA);
    // layer 2: t2 = relu(agg(t1)).W2 + b2
    fused_agg_gemm<<<fused_grid, 256, 0, stream>>>(bufA, csr, row_ptr, dis, W2, b2, bufB);
    // layer 3: t3 = relu(agg(t2)).W3 + b3
    fused_agg_gemm<<<fused_grid, 256, 0, stream>>>(bufB, csr, row_ptr, dis, W3, b3, bufA);
    // tail: pooled += relu(agg(t3)) per graph
    fused_agg_pool<<<agg3_grid, 256, 0, stream>>>(bufA, csr, row_ptr, dis, batch, pooled);
    // head
    head<<<G, 128, 0, stream>>>(pooled, batch, Wl, bl, out);
}

// Round 6
// 394.127 us; speedup vs baseline: 10.0311x; 1.0069x over previous
//
#include <hip/hip_runtime.h>

// Problem constants (fixed by the reference's setup_inputs)
constexpr int N = 40000;    // nodes
constexpr int E = 640000;   // edges
constexpr int G = 64;       // graphs
constexpr int H = 128;      // hidden = F_IN

constexpr int NB = (N + 255) / 256;   // 157 blocks over nodes

// ---------------------------------------------------------------------------
__global__ void zero_int(int* __restrict__ p, int n) {
    int i = blockIdx.x * blockDim.x + threadIdx.x;
    if (i < n) p[i] = 0;
}

__global__ void zero_f32(float* __restrict__ p, int n) {
    int i = blockIdx.x * blockDim.x + threadIdx.x;
    if (i < n) p[i] = 0.0f;
}

// deg[col[e]] += 1 for each edge (self-loop +1 added in finalize)
__global__ void count_deg(const int* __restrict__ col, int* __restrict__ deg) {
    int e = blockIdx.x * blockDim.x + threadIdx.x;
    if (e < E) atomicAdd(&deg[col[e]], 1);
}

// dis[i] = rsqrt(deg[i] + 1)
__global__ void finalize_dis(const int* __restrict__ deg, float* __restrict__ dis) {
    int i = blockIdx.x * blockDim.x + threadIdx.x;
    if (i < N) dis[i] = rsqrtf((float)(deg[i] + 1));
}

// per-block sums of deg for the scan
__global__ void block_sum(const int* __restrict__ deg, int* __restrict__ part) {
    __shared__ int s[256];
    int i = blockIdx.x * 256 + threadIdx.x;
    s[threadIdx.x] = (i < N) ? deg[i] : 0;
    __syncthreads();
    for (int off = 128; off > 0; off >>= 1) {
        if (threadIdx.x < off) s[threadIdx.x] += s[threadIdx.x + off];
        __syncthreads();
    }
    if (threadIdx.x == 0) part[blockIdx.x] = s[0];
}

// serial exclusive scan of the 157 partials (tiny)
__global__ void scan_part(int* __restrict__ part, int* __restrict__ row_ptr) {
    if (threadIdx.x == 0 && blockIdx.x == 0) {
        int run = 0;
        for (int b = 0; b < NB; ++b) { int t = part[b]; part[b] = run; run += t; }
        row_ptr[N] = run;   // == E
    }
}

// block-level exclusive scan + partial offset -> row_ptr, cursor
__global__ void scan_write(const int* __restrict__ deg, const int* __restrict__ part,
                           int* __restrict__ row_ptr, int* __restrict__ cursor) {
    __shared__ int s[256];
    int i = blockIdx.x * 256 + threadIdx.x;
    int val = (i < N) ? deg[i] : 0;
    s[threadIdx.x] = val;
    __syncthreads();
    for (int off = 1; off < 256; off <<= 1) {
        int t = (threadIdx.x >= off) ? s[threadIdx.x - off] : 0;
        __syncthreads();
        s[threadIdx.x] += t;
        __syncthreads();
    }
    if (i < N) {
        int excl = s[threadIdx.x] - val + part[blockIdx.x];
        row_ptr[i] = excl;
        cursor[i] = excl;
    }
}

// fill CSR: for each edge, place (src, norm) into its destination's segment
__global__ void fill_csr(const int* __restrict__ row, const int* __restrict__ col,
                         const float* __restrict__ dis, int* __restrict__ cursor,
                         int2* __restrict__ csr) {
    int e = blockIdx.x * blockDim.x + threadIdx.x;
    if (e >= E) return;
    int r = row[e], c = col[e];
    float w = dis[r] * dis[c];
    int p = atomicAdd(&cursor[c], 1);
    csr[p] = make_int2(r, __float_as_int(w));
}

// ---------------------------------------------------------------------------
// Standalone GEMM (layer 1): Y = X.W + b. NO LDS — X row reads are
// broadcast-coalesced, W reads are coalesced across jg and L1/L2-hot
// (64 KB shared by all blocks). Zero LDS -> occupancy not LDS-capped.
__global__ __launch_bounds__(256) void gemm_bias(const float* __restrict__ X,
                                                 const float* __restrict__ W,
                                                 const float* __restrict__ b,
                                                 float* __restrict__ Y) {
    const int tid = threadIdx.x;
    const int jg = tid & 31;    // col group: cols 4*jg..4*jg+3
    const int rs = tid >> 5;    // row slot: 8 slots x 4 rows
    const int r0 = blockIdx.x * 32 + rs * 4;

    const float4* W4 = reinterpret_cast<const float4*>(W);
    const float4* X4 = reinterpret_cast<const float4*>(X);

    const float4 bv = reinterpret_cast<const float4*>(b)[jg];
    float4 acc0 = bv, acc1 = bv, acc2 = bv, acc3 = bv;

    #pragma unroll 4
    for (int k4 = 0; k4 < 32; ++k4) {
        float4 xv0 = X4[(size_t)(r0 + 0) * 32 + k4];
        float4 xv1 = X4[(size_t)(r0 + 1) * 32 + k4];
        float4 xv2 = X4[(size_t)(r0 + 2) * 32 + k4];
        float4 xv3 = X4[(size_t)(r0 + 3) * 32 + k4];
        #pragma unroll
        for (int kk = 0; kk < 4; ++kk) {
            float4 wv = W4[(k4 * 4 + kk) * 32 + jg];
            float xs0 = (kk==0)?xv0.x:(kk==1)?xv0.y:(kk==2)?xv0.z:xv0.w;
            float xs1 = (kk==0)?xv1.x:(kk==1)?xv1.y:(kk==2)?xv1.z:xv1.w;
            float xs2 = (kk==0)?xv2.x:(kk==1)?xv2.y:(kk==2)?xv2.z:xv2.w;
            float xs3 = (kk==0)?xv3.x:(kk==1)?xv3.y:(kk==2)?xv3.z:xv3.w;
            acc0.x = fmaf(xs0, wv.x, acc0.x); acc0.y = fmaf(xs0, wv.y, acc0.y);
            acc0.z = fmaf(xs0, wv.z, acc0.z); acc0.w = fmaf(xs0, wv.w, acc0.w);
            acc1.x = fmaf(xs1, wv.x, acc1.x); acc1.y = fmaf(xs1, wv.y, acc1.y);
            acc1.z = fmaf(xs1, wv.z, acc1.z); acc1.w = fmaf(xs1, wv.w, acc1.w);
            acc2.x = fmaf(xs2, wv.x, acc2.x); acc2.y = fmaf(xs2, wv.y, acc2.y);
            acc2.z = fmaf(xs2, wv.z, acc2.z); acc2.w = fmaf(xs2, wv.w, acc2.w);
            acc3.x = fmaf(xs3, wv.x, acc3.x); acc3.y = fmaf(xs3, wv.y, acc3.y);
            acc3.z = fmaf(xs3, wv.z, acc3.z); acc3.w = fmaf(xs3, wv.w, acc3.w);
        }
    }

    float4* Y4 = reinterpret_cast<float4*>(Y);
    Y4[(size_t)(r0 + 0) * 32 + jg] = acc0;
    Y4[(size_t)(r0 + 1) * 32 + jg] = acc1;
    Y4[(size_t)(r0 + 2) * 32 + jg] = acc2;
    Y4[(size_t)(r0 + 3) * 32 + jg] = acc3;
}

// ---------------------------------------------------------------------------
// Fused layer: t_out = relu(agg(t_in)) . W + b
// Phase A: aggregate 32 nodes + relu -> 16 KB LDS tile (the only LDS).
// Phase B: tile . W with W read directly from global (L1/L2-hot, coalesced).
// One barrier total; LDS 16 KB/block to keep gather occupancy high.
__global__ __launch_bounds__(256) void fused_agg_gemm(const float* __restrict__ t_in,
                                                      const int2* __restrict__ csr,
                                                      const int* __restrict__ row_ptr,
                                                      const float* __restrict__ dis,
                                                      const float* __restrict__ W,
                                                      const float* __restrict__ b,
                                                      float* __restrict__ t_out) {
    __shared__ float4 tile[32 * 32];  // 16 KB: 32 nodes x 128 feats
    const int tid = threadIdx.x;
    const int node0 = blockIdx.x * 32;
    const float4* h4 = reinterpret_cast<const float4*>(t_in);

    {   // ---- Phase A: aggregate + relu ----
        const int c  = tid & 31;
        const int nl = tid >> 5;
        #pragma unroll
        for (int sub = 0; sub < 4; ++sub) {
            const int local = sub * 8 + nl;
            const int i = node0 + local;
            float d = dis[i];
            float sl = d * d;
            float4 acc = h4[(size_t)i * 32 + c];
            acc.x *= sl; acc.y *= sl; acc.z *= sl; acc.w *= sl;
            int p  = row_ptr[i];
            int p1 = row_ptr[i + 1];
            for (; p + 2 <= p1; p += 2) {
                int2 e0 = csr[p];
                int2 e1 = csr[p + 1];
                float4 v0 = h4[(size_t)e0.x * 32 + c];
                float4 v1 = h4[(size_t)e1.x * 32 + c];
                float w0 = __int_as_float(e0.y);
                float w1 = __int_as_float(e1.y);
                acc.x = fmaf(v0.x, w0, acc.x); acc.y = fmaf(v0.y, w0, acc.y);
                acc.z = fmaf(v0.z, w0, acc.z); acc.w = fmaf(v0.w, w0, acc.w);
                acc.x = fmaf(v1.x, w1, acc.x); acc.y = fmaf(v1.y, w1, acc.y);
                acc.z = fmaf(v1.z, w1, acc.z); acc.w = fmaf(v1.w, w1, acc.w);
            }
            if (p < p1) {
                int2 e0 = csr[p];
                float4 v0 = h4[(size_t)e0.x * 32 + c];
                float w0 = __int_as_float(e0.y);
                acc.x = fmaf(v0.x, w0, acc.x); acc.y = fmaf(v0.y, w0, acc.y);
                acc.z = fmaf(v0.z, w0, acc.z); acc.w = fmaf(v0.w, w0, acc.w);
            }
            acc.x = fmaxf(acc.x, 0.f); acc.y = fmaxf(acc.y, 0.f);
            acc.z = fmaxf(acc.z, 0.f); acc.w = fmaxf(acc.w, 0.f);
            tile[local * 32 + c] = acc;
        }
    }
    __syncthreads();

    // ---- Phase B: GEMM from LDS tile, W from global ----
    const int jg = tid & 31;
    const int rs = tid >> 5;
    const int r0 = rs * 4;   // local row base
    const float4* W4 = reinterpret_cast<const float4*>(W);
    const float4 bv = reinterpret_cast<const float4*>(b)[jg];
    float4 acc0 = bv, acc1 = bv, acc2 = bv, acc3 = bv;

    #pragma unroll 4
    for (int k4 = 0; k4 < 32; ++k4) {
        float4 xv0 = tile[(r0 + 0) * 32 + k4];
        float4 xv1 = tile[(r0 + 1) * 32 + k4];
        float4 xv2 = tile[(r0 + 2) * 32 + k4];
        float4 xv3 = tile[(r0 + 3) * 32 + k4];
        #pragma unroll
        for (int kk = 0; kk < 4; ++kk) {
            float4 wv = W4[(k4 * 4 + kk) * 32 + jg];
            float xs0 = (kk==0)?xv0.x:(kk==1)?xv0.y:(kk==2)?xv0.z:xv0.w;
            float xs1 = (kk==0)?xv1.x:(kk==1)?xv1.y:(kk==2)?xv1.z:xv1.w;
            float xs2 = (kk==0)?xv2.x:(kk==1)?xv2.y:(kk==2)?xv2.z:xv2.w;
            float xs3 = (kk==0)?xv3.x:(kk==1)?xv3.y:(kk==2)?xv3.z:xv3.w;
            acc0.x = fmaf(xs0, wv.x, acc0.x); acc0.y = fmaf(xs0, wv.y, acc0.y);
            acc0.z = fmaf(xs0, wv.z, acc0.z); acc0.w = fmaf(xs0, wv.w, acc0.w);
            acc1.x = fmaf(xs1, wv.x, acc1.x); acc1.y = fmaf(xs1, wv.y, acc1.y);
            acc1.z = fmaf(xs1, wv.z, acc1.z); acc1.w = fmaf(xs1, wv.w, acc1.w);
            acc2.x = fmaf(xs2, wv.x, acc2.x); acc2.y = fmaf(xs2, wv.y, acc2.y);
            acc2.z = fmaf(xs2, wv.z, acc2.z); acc2.w = fmaf(xs2, wv.w, acc2.w);
            acc3.x = fmaf(xs3, wv.x, acc3.x); acc3.y = fmaf(xs3, wv.y, acc3.y);
            acc3.z = fmaf(xs3, wv.z, acc3.z); acc3.w = fmaf(xs3, wv.w, acc3.w);
        }
    }

    float4* Y4 = reinterpret_cast<float4*>(t_out);
    const int gr0 = node0 + r0;
    Y4[(size_t)(gr0 + 0) * 32 + jg] = acc0;
    Y4[(size_t)(gr0 + 1) * 32 + jg] = acc1;
    Y4[(size_t)(gr0 + 2) * 32 + jg] = acc2;
    Y4[(size_t)(gr0 + 3) * 32 + jg] = acc3;
}

// ---------------------------------------------------------------------------
// Fused layer 3 tail: relu(agg(t_in)) accumulated straight into pooled[G][H]
// (run-flush atomics; batch sorted -> ~1 flush per block). h3 never hits HBM.
__global__ __launch_bounds__(256) void fused_agg_pool(const float* __restrict__ t_in,
                                                      const int2* __restrict__ csr,
                                                      const int* __restrict__ row_ptr,
                                                      const float* __restrict__ dis,
                                                      const int* __restrict__ batch,
                                                      float* __restrict__ pooled) {
    __shared__ float4 tile[8 * 32];   // 4 KB: 8 nodes x 128 feats
    const int tid = threadIdx.x;
    const int c  = tid & 31;
    const int nl = tid >> 5;
    const int i0 = blockIdx.x * 8;
    const int i = i0 + nl;
    const float4* h4 = reinterpret_cast<const float4*>(t_in);

    float d = dis[i];
    float sl = d * d;
    float4 acc = h4[(size_t)i * 32 + c];
    acc.x *= sl; acc.y *= sl; acc.z *= sl; acc.w *= sl;
    int p  = row_ptr[i];
    int p1 = row_ptr[i + 1];
    for (; p + 2 <= p1; p += 2) {
        int2 e0 = csr[p];
        int2 e1 = csr[p + 1];
        float4 v0 = h4[(size_t)e0.x * 32 + c];
        float4 v1 = h4[(size_t)e1.x * 32 + c];
        float w0 = __int_as_float(e0.y);
        float w1 = __int_as_float(e1.y);
        acc.x = fmaf(v0.x, w0, acc.x); acc.y = fmaf(v0.y, w0, acc.y);
        acc.z = fmaf(v0.z, w0, acc.z); acc.w = fmaf(v0.w, w0, acc.w);
        acc.x = fmaf(v1.x, w1, acc.x); acc.y = fmaf(v1.y, w1, acc.y);
        acc.z = fmaf(v1.z, w1, acc.z); acc.w = fmaf(v1.w, w1, acc.w);
    }
    if (p < p1) {
        int2 e0 = csr[p];
        float4 v0 = h4[(size_t)e0.x * 32 + c];
        float w0 = __int_as_float(e0.y);
        acc.x = fmaf(v0.x, w0, acc.x); acc.y = fmaf(v0.y, w0, acc.y);
        acc.z = fmaf(v0.z, w0, acc.z); acc.w = fmaf(v0.w, w0, acc.w);
    }
    acc.x = fmaxf(acc.x, 0.f); acc.y = fmaxf(acc.y, 0.f);
    acc.z = fmaxf(acc.z, 0.f); acc.w = fmaxf(acc.w, 0.f);
    tile[nl * 32 + c] = acc;
    __syncthreads();

    if (tid < 128) {
        const int j = tid;
        const float* tf = reinterpret_cast<const float*>(tile);
        int cur = batch[i0];
        float s = 0.0f;
        #pragma unroll
        for (int r = 0; r < 8; ++r) {
            int g = batch[i0 + r];
            if (g != cur) { atomicAdd(&pooled[cur * H + j], s); s = 0.0f; cur = g; }
            s += tf[r * 128 + j];
        }
        atomicAdd(&pooled[cur * H + j], s);
    }
}

// Head: out[g] = (pooled[g]/cnt[g]) . Wl + bl ; cnt via binary search.
__global__ __launch_bounds__(128) void head(const float* __restrict__ pooled,
                                            const int* __restrict__ batch,
                                            const float* __restrict__ Wl,
                                            const float* __restrict__ bl,
                                            float* __restrict__ out) {
    const int g = blockIdx.x;
    const int j = threadIdx.x;
    __shared__ int bounds[2];
    if (j < 2) {
        int target = g + j;
        int lo = 0, hi = N;
        while (lo < hi) {
            int mid = (lo + hi) >> 1;
            if (batch[mid] < target) lo = mid + 1; else hi = mid;
        }
        bounds[j] = lo;
    }
    __syncthreads();
    float cnt = fmaxf((float)(bounds[1] - bounds[0]), 1.0f);
    float val = (pooled[g * H + j] / cnt) * Wl[j];
    __shared__ float red[128];
    red[j] = val;
    __syncthreads();
    #pragma unroll
    for (int s = 64; s > 0; s >>= 1) {
        if (j < s) red[j] += red[j + s];
        __syncthreads();
    }
    if (j == 0) out[g] = red[0] + bl[0];
}

// ---------------------------------------------------------------------------
extern "C" void kernel_launch(void* const* d_in, const int* in_sizes, int n_in,
                              void* d_out, int out_size, void* d_ws, size_t ws_size,
                              hipStream_t stream) {
    const float* x     = (const float*)d_in[0];
    const int*   ei    = (const int*)  d_in[1];   // [2, E] flat
    const int*   batch = (const int*)  d_in[2];
    const float* W1 = (const float*)d_in[4];
    const float* b1 = (const float*)d_in[5];
    const float* W2 = (const float*)d_in[6];
    const float* b2 = (const float*)d_in[7];
    const float* W3 = (const float*)d_in[8];
    const float* b3 = (const float*)d_in[9];
    const float* Wl = (const float*)d_in[10];
    const float* bl = (const float*)d_in[11];
    float* out = (float*)d_out;

    const int* row = ei;       // source
    const int* col = ei + E;   // target

    // workspace layout (256B aligned); ~47 MB total
    auto align256 = [](size_t v) { return (v + 255) & ~(size_t)255; };
    char* ws = (char*)d_ws;
    size_t off = 0;
    int*   deg     = (int*)  (ws + off); off += align256((size_t)N * 4);
    float* dis     = (float*)(ws + off); off += align256((size_t)N * 4);
    int*   row_ptr = (int*)  (ws + off); off += align256((size_t)(N + 1) * 4);
    int*   cursor  = (int*)  (ws + off); off += align256((size_t)N * 4);
    int*   part    = (int*)  (ws + off); off += align256((size_t)NB * 4);
    int2*  csr     = (int2*) (ws + off); off += align256((size_t)E * 8);
    float* bufA    = (float*)(ws + off); off += align256((size_t)N * H * 4);
    float* bufB    = (float*)(ws + off); off += align256((size_t)N * H * 4);
    float* pooled  = (float*)(ws + off); off += align256((size_t)G * H * 4);
    (void)ws_size; (void)n_in; (void)in_sizes; (void)out_size;

    // --- CSR + norm precompute ---
    zero_int<<<NB, 256, 0, stream>>>(deg, N);
    count_deg<<<(E + 255) / 256, 256, 0, stream>>>(col, deg);
    finalize_dis<<<NB, 256, 0, stream>>>(deg, dis);
    block_sum<<<NB, 256, 0, stream>>>(deg, part);
    scan_part<<<1, 64, 0, stream>>>(part, row_ptr);
    scan_write<<<NB, 256, 0, stream>>>(deg, part, row_ptr, cursor);
    fill_csr<<<(E + 255) / 256, 256, 0, stream>>>(row, col, dis, cursor, csr);

    // pooled must be zero before fused_agg_pool accumulates
    zero_f32<<<(G * H + 255) / 256, 256, 0, stream>>>(pooled, G * H);

    const int gemm_grid  = N / 32;   // 1250
    const int fused_grid = N / 32;   // 1250
    const int agg3_grid  = N / 8;    // 5000

    // layer 1: t1 = x.W1 + b1
    gemm_bias<<<gemm_grid, 256, 0, stream>>>(x, W1, b1, bufA);
    // layer 2: t2 = relu(agg(t1)).W2 + b2
    fused_agg_gemm<<<fused_grid, 256, 0, stream>>>(bufA, csr, row_ptr, dis, W2, b2, bufB);
    // layer 3: t3 = relu(agg(t2)).W3 + b3
    fused_agg_gemm<<<fused_grid, 256, 0, stream>>>(bufB, csr, row_ptr, dis, W3, b3, bufA);
    // tail: pooled += relu(agg(t3)) per graph
    fused_agg_pool<<<agg3_grid, 256, 0, stream>>>(bufA, csr, row_ptr, dis, batch, pooled);
    // head
    head<<<G, 128, 0, stream>>>(pooled, batch, Wl, bl, out);
}

// Round 7
// 330.779 us; speedup vs baseline: 11.9522x; 1.1915x over previous
//
#include <hip/hip_runtime.h>

// Problem constants (fixed by the reference's setup_inputs)
constexpr int N = 40000;    // nodes
constexpr int E = 640000;   // edges
constexpr int G = 64;       // graphs
constexpr int H = 128;      // hidden = F_IN

constexpr int NB = (N + 255) / 256;   // 157 blocks over nodes

// ---------------------------------------------------------------------------
// bf16 helpers (manual, exact bf16->f32 via shift; f32->bf16 RNE)
__device__ __forceinline__ float bfl(unsigned u) {   // low bf16 of a uint
    return __uint_as_float(u << 16);
}
__device__ __forceinline__ float bfh(unsigned u) {   // high bf16 of a uint
    return __uint_as_float(u & 0xffff0000u);
}
__device__ __forceinline__ unsigned pack_bf16x2(float a, float b) {
    unsigned ua = __float_as_uint(a);
    unsigned ub = __float_as_uint(b);
    ua += 0x7fffu + ((ua >> 16) & 1u);
    ub += 0x7fffu + ((ub >> 16) & 1u);
    return (ua >> 16) | (ub & 0xffff0000u);
}

// ---------------------------------------------------------------------------
__global__ void zero_int(int* __restrict__ p, int n) {
    int i = blockIdx.x * blockDim.x + threadIdx.x;
    if (i < n) p[i] = 0;
}

__global__ void zero_f32(float* __restrict__ p, int n) {
    int i = blockIdx.x * blockDim.x + threadIdx.x;
    if (i < n) p[i] = 0.0f;
}

// deg[col[e]] += 1 for each edge (self-loop +1 added in finalize)
__global__ void count_deg(const int* __restrict__ col, int* __restrict__ deg) {
    int e = blockIdx.x * blockDim.x + threadIdx.x;
    if (e < E) atomicAdd(&deg[col[e]], 1);
}

// dis[i] = rsqrt(deg[i]+1)  AND  per-block sums of deg for the scan (fused)
__global__ void dis_and_block_sum(const int* __restrict__ deg, float* __restrict__ dis,
                                  int* __restrict__ part) {
    __shared__ int s[256];
    int i = blockIdx.x * 256 + threadIdx.x;
    int d = (i < N) ? deg[i] : 0;
    if (i < N) dis[i] = rsqrtf((float)(d + 1));
    s[threadIdx.x] = d;
    __syncthreads();
    for (int off = 128; off > 0; off >>= 1) {
        if (threadIdx.x < off) s[threadIdx.x] += s[threadIdx.x + off];
        __syncthreads();
    }
    if (threadIdx.x == 0) part[blockIdx.x] = s[0];
}

// serial exclusive scan of the 157 partials (tiny)
__global__ void scan_part(int* __restrict__ part, int* __restrict__ row_ptr) {
    if (threadIdx.x == 0 && blockIdx.x == 0) {
        int run = 0;
        for (int b = 0; b < NB; ++b) { int t = part[b]; part[b] = run; run += t; }
        row_ptr[N] = run;   // == E
    }
}

// block-level exclusive scan + partial offset -> row_ptr, cursor
__global__ void scan_write(const int* __restrict__ deg, const int* __restrict__ part,
                           int* __restrict__ row_ptr, int* __restrict__ cursor) {
    __shared__ int s[256];
    int i = blockIdx.x * 256 + threadIdx.x;
    int val = (i < N) ? deg[i] : 0;
    s[threadIdx.x] = val;
    __syncthreads();
    for (int off = 1; off < 256; off <<= 1) {
        int t = (threadIdx.x >= off) ? s[threadIdx.x - off] : 0;
        __syncthreads();
        s[threadIdx.x] += t;
        __syncthreads();
    }
    if (i < N) {
        int excl = s[threadIdx.x] - val + part[blockIdx.x];
        row_ptr[i] = excl;
        cursor[i] = excl;
    }
}

// fill CSR: for each edge, place (src, norm) into its destination's segment
__global__ void fill_csr(const int* __restrict__ row, const int* __restrict__ col,
                         const float* __restrict__ dis, int* __restrict__ cursor,
                         int2* __restrict__ csr) {
    int e = blockIdx.x * blockDim.x + threadIdx.x;
    if (e >= E) return;
    int r = row[e], c = col[e];
    float w = dis[r] * dis[c];
    int p = atomicAdd(&cursor[c], 1);
    csr[p] = make_int2(r, __float_as_int(w));
}

// ---------------------------------------------------------------------------
// Per-lane gather micro-op: acc += h_bf16[src][4c..4c+3] * w
__device__ __forceinline__ void gather_fma(const uint2* __restrict__ hb2, int src, int c,
                                           float w, float4& acc) {
    uint2 raw = hb2[(size_t)src * 32 + c];
    acc.x = fmaf(bfl(raw.x), w, acc.x);
    acc.y = fmaf(bfh(raw.x), w, acc.y);
    acc.z = fmaf(bfl(raw.y), w, acc.z);
    acc.w = fmaf(bfh(raw.y), w, acc.w);
}

// Full aggregation for one node (lane c of 32): fp32 accumulator from bf16 h.
__device__ __forceinline__ float4 aggregate_node(const uint2* __restrict__ hb2,
                                                 const int2* __restrict__ csr,
                                                 const int* __restrict__ row_ptr,
                                                 const float* __restrict__ dis,
                                                 int i, int c) {
    float d = dis[i];
    float sl = d * d;
    float4 acc = make_float4(0.f, 0.f, 0.f, 0.f);
    gather_fma(hb2, i, c, sl, acc);   // self-loop
    int p  = row_ptr[i];
    int p1 = row_ptr[i + 1];
    for (; p + 4 <= p1; p += 4) {     // 4 outstanding row loads per lane
        int2 e0 = csr[p], e1 = csr[p + 1], e2 = csr[p + 2], e3 = csr[p + 3];
        uint2 r0 = hb2[(size_t)e0.x * 32 + c];
        uint2 r1 = hb2[(size_t)e1.x * 32 + c];
        uint2 r2 = hb2[(size_t)e2.x * 32 + c];
        uint2 r3 = hb2[(size_t)e3.x * 32 + c];
        float w0 = __int_as_float(e0.y), w1 = __int_as_float(e1.y);
        float w2 = __int_as_float(e2.y), w3 = __int_as_float(e3.y);
        acc.x = fmaf(bfl(r0.x), w0, acc.x); acc.y = fmaf(bfh(r0.x), w0, acc.y);
        acc.z = fmaf(bfl(r0.y), w0, acc.z); acc.w = fmaf(bfh(r0.y), w0, acc.w);
        acc.x = fmaf(bfl(r1.x), w1, acc.x); acc.y = fmaf(bfh(r1.x), w1, acc.y);
        acc.z = fmaf(bfl(r1.y), w1, acc.z); acc.w = fmaf(bfh(r1.y), w1, acc.w);
        acc.x = fmaf(bfl(r2.x), w2, acc.x); acc.y = fmaf(bfh(r2.x), w2, acc.y);
        acc.z = fmaf(bfl(r2.y), w2, acc.z); acc.w = fmaf(bfh(r2.y), w2, acc.w);
        acc.x = fmaf(bfl(r3.x), w3, acc.x); acc.y = fmaf(bfh(r3.x), w3, acc.y);
        acc.z = fmaf(bfl(r3.y), w3, acc.z); acc.w = fmaf(bfh(r3.y), w3, acc.w);
    }
    for (; p < p1; ++p) {
        int2 e0 = csr[p];
        gather_fma(hb2, e0.x, c, __int_as_float(e0.y), acc);
    }
    return acc;
}

// ---------------------------------------------------------------------------
// Layer-1 GEMM: Y_bf16 = X_f32 . W + b. No LDS (W is L1/L2-hot, coalesced).
__global__ __launch_bounds__(256) void gemm_bias(const float* __restrict__ X,
                                                 const float* __restrict__ W,
                                                 const float* __restrict__ b,
                                                 uint2* __restrict__ Y) {
    const int tid = threadIdx.x;
    const int jg = tid & 31;    // col group: cols 4*jg..4*jg+3
    const int rs = tid >> 5;    // row slot: 8 slots x 4 rows
    const int r0 = blockIdx.x * 32 + rs * 4;

    const float4* W4 = reinterpret_cast<const float4*>(W);
    const float4* X4 = reinterpret_cast<const float4*>(X);

    const float4 bv = reinterpret_cast<const float4*>(b)[jg];
    float4 acc0 = bv, acc1 = bv, acc2 = bv, acc3 = bv;

    #pragma unroll 4
    for (int k4 = 0; k4 < 32; ++k4) {
        float4 xv0 = X4[(size_t)(r0 + 0) * 32 + k4];
        float4 xv1 = X4[(size_t)(r0 + 1) * 32 + k4];
        float4 xv2 = X4[(size_t)(r0 + 2) * 32 + k4];
        float4 xv3 = X4[(size_t)(r0 + 3) * 32 + k4];
        #pragma unroll
        for (int kk = 0; kk < 4; ++kk) {
            float4 wv = W4[(k4 * 4 + kk) * 32 + jg];
            float xs0 = (kk==0)?xv0.x:(kk==1)?xv0.y:(kk==2)?xv0.z:xv0.w;
            float xs1 = (kk==0)?xv1.x:(kk==1)?xv1.y:(kk==2)?xv1.z:xv1.w;
            float xs2 = (kk==0)?xv2.x:(kk==1)?xv2.y:(kk==2)?xv2.z:xv2.w;
            float xs3 = (kk==0)?xv3.x:(kk==1)?xv3.y:(kk==2)?xv3.z:xv3.w;
            acc0.x = fmaf(xs0, wv.x, acc0.x); acc0.y = fmaf(xs0, wv.y, acc0.y);
            acc0.z = fmaf(xs0, wv.z, acc0.z); acc0.w = fmaf(xs0, wv.w, acc0.w);
            acc1.x = fmaf(xs1, wv.x, acc1.x); acc1.y = fmaf(xs1, wv.y, acc1.y);
            acc1.z = fmaf(xs1, wv.z, acc1.z); acc1.w = fmaf(xs1, wv.w, acc1.w);
            acc2.x = fmaf(xs2, wv.x, acc2.x); acc2.y = fmaf(xs2, wv.y, acc2.y);
            acc2.z = fmaf(xs2, wv.z, acc2.z); acc2.w = fmaf(xs2, wv.w, acc2.w);
            acc3.x = fmaf(xs3, wv.x, acc3.x); acc3.y = fmaf(xs3, wv.y, acc3.y);
            acc3.z = fmaf(xs3, wv.z, acc3.z); acc3.w = fmaf(xs3, wv.w, acc3.w);
        }
    }

    Y[(size_t)(r0 + 0) * 32 + jg] = make_uint2(pack_bf16x2(acc0.x, acc0.y), pack_bf16x2(acc0.z, acc0.w));
    Y[(size_t)(r0 + 1) * 32 + jg] = make_uint2(pack_bf16x2(acc1.x, acc1.y), pack_bf16x2(acc1.z, acc1.w));
    Y[(size_t)(r0 + 2) * 32 + jg] = make_uint2(pack_bf16x2(acc2.x, acc2.y), pack_bf16x2(acc2.z, acc2.w));
    Y[(size_t)(r0 + 3) * 32 + jg] = make_uint2(pack_bf16x2(acc3.x, acc3.y), pack_bf16x2(acc3.z, acc3.w));
}

// ---------------------------------------------------------------------------
// Fused layer: t_out_bf16 = relu(agg(t_in_bf16)) . W + b
// Phase A: aggregate 32 nodes (bf16 gather, fp32 acc) + relu -> 16 KB fp32 tile.
// Phase B: tile . W (W from global, L1/L2-hot), bf16 store.
__global__ __launch_bounds__(256) void fused_agg_gemm(const uint2* __restrict__ t_in,
                                                      const int2* __restrict__ csr,
                                                      const int* __restrict__ row_ptr,
                                                      const float* __restrict__ dis,
                                                      const float* __restrict__ W,
                                                      const float* __restrict__ b,
                                                      uint2* __restrict__ t_out) {
    __shared__ float4 tile[32 * 32];  // 16 KB: 32 nodes x 128 feats (fp32)
    const int tid = threadIdx.x;
    const int node0 = blockIdx.x * 32;

    {   // ---- Phase A ----
        const int c  = tid & 31;
        const int nl = tid >> 5;
        #pragma unroll
        for (int sub = 0; sub < 4; ++sub) {
            const int local = sub * 8 + nl;
            float4 acc = aggregate_node(t_in, csr, row_ptr, dis, node0 + local, c);
            acc.x = fmaxf(acc.x, 0.f); acc.y = fmaxf(acc.y, 0.f);
            acc.z = fmaxf(acc.z, 0.f); acc.w = fmaxf(acc.w, 0.f);
            tile[local * 32 + c] = acc;
        }
    }
    __syncthreads();

    // ---- Phase B ----
    const int jg = tid & 31;
    const int rs = tid >> 5;
    const int r0 = rs * 4;   // local row base
    const float4* W4 = reinterpret_cast<const float4*>(W);
    const float4 bv = reinterpret_cast<const float4*>(b)[jg];
    float4 acc0 = bv, acc1 = bv, acc2 = bv, acc3 = bv;

    #pragma unroll 4
    for (int k4 = 0; k4 < 32; ++k4) {
        float4 xv0 = tile[(r0 + 0) * 32 + k4];
        float4 xv1 = tile[(r0 + 1) * 32 + k4];
        float4 xv2 = tile[(r0 + 2) * 32 + k4];
        float4 xv3 = tile[(r0 + 3) * 32 + k4];
        #pragma unroll
        for (int kk = 0; kk < 4; ++kk) {
            float4 wv = W4[(k4 * 4 + kk) * 32 + jg];
            float xs0 = (kk==0)?xv0.x:(kk==1)?xv0.y:(kk==2)?xv0.z:xv0.w;
            float xs1 = (kk==0)?xv1.x:(kk==1)?xv1.y:(kk==2)?xv1.z:xv1.w;
            float xs2 = (kk==0)?xv2.x:(kk==1)?xv2.y:(kk==2)?xv2.z:xv2.w;
            float xs3 = (kk==0)?xv3.x:(kk==1)?xv3.y:(kk==2)?xv3.z:xv3.w;
            acc0.x = fmaf(xs0, wv.x, acc0.x); acc0.y = fmaf(xs0, wv.y, acc0.y);
            acc0.z = fmaf(xs0, wv.z, acc0.z); acc0.w = fmaf(xs0, wv.w, acc0.w);
            acc1.x = fmaf(xs1, wv.x, acc1.x); acc1.y = fmaf(xs1, wv.y, acc1.y);
            acc1.z = fmaf(xs1, wv.z, acc1.z); acc1.w = fmaf(xs1, wv.w, acc1.w);
            acc2.x = fmaf(xs2, wv.x, acc2.x); acc2.y = fmaf(xs2, wv.y, acc2.y);
            acc2.z = fmaf(xs2, wv.z, acc2.z); acc2.w = fmaf(xs2, wv.w, acc2.w);
            acc3.x = fmaf(xs3, wv.x, acc3.x); acc3.y = fmaf(xs3, wv.y, acc3.y);
            acc3.z = fmaf(xs3, wv.z, acc3.z); acc3.w = fmaf(xs3, wv.w, acc3.w);
        }
    }

    const int gr0 = node0 + r0;
    t_out[(size_t)(gr0 + 0) * 32 + jg] = make_uint2(pack_bf16x2(acc0.x, acc0.y), pack_bf16x2(acc0.z, acc0.w));
    t_out[(size_t)(gr0 + 1) * 32 + jg] = make_uint2(pack_bf16x2(acc1.x, acc1.y), pack_bf16x2(acc1.z, acc1.w));
    t_out[(size_t)(gr0 + 2) * 32 + jg] = make_uint2(pack_bf16x2(acc2.x, acc2.y), pack_bf16x2(acc2.z, acc2.w));
    t_out[(size_t)(gr0 + 3) * 32 + jg] = make_uint2(pack_bf16x2(acc3.x, acc3.y), pack_bf16x2(acc3.z, acc3.w));
}

// ---------------------------------------------------------------------------
// Fused layer 3 tail: relu(agg(t_in_bf16)) accumulated into pooled[G][H] (fp32).
__global__ __launch_bounds__(256) void fused_agg_pool(const uint2* __restrict__ t_in,
                                                      const int2* __restrict__ csr,
                                                      const int* __restrict__ row_ptr,
                                                      const float* __restrict__ dis,
                                                      const int* __restrict__ batch,
                                                      float* __restrict__ pooled) {
    __shared__ float4 tile[8 * 32];   // 4 KB: 8 nodes x 128 feats
    const int tid = threadIdx.x;
    const int c  = tid & 31;
    const int nl = tid >> 5;
    const int i0 = blockIdx.x * 8;

    float4 acc = aggregate_node(t_in, csr, row_ptr, dis, i0 + nl, c);
    acc.x = fmaxf(acc.x, 0.f); acc.y = fmaxf(acc.y, 0.f);
    acc.z = fmaxf(acc.z, 0.f); acc.w = fmaxf(acc.w, 0.f);
    tile[nl * 32 + c] = acc;
    __syncthreads();

    if (tid < 128) {
        const int j = tid;
        const float* tf = reinterpret_cast<const float*>(tile);
        int cur = batch[i0];
        float s = 0.0f;
        #pragma unroll
        for (int r = 0; r < 8; ++r) {
            int g = batch[i0 + r];
            if (g != cur) { atomicAdd(&pooled[cur * H + j], s); s = 0.0f; cur = g; }
            s += tf[r * 128 + j];
        }
        atomicAdd(&pooled[cur * H + j], s);
    }
}

// Head: out[g] = (pooled[g]/cnt[g]) . Wl + bl ; cnt via binary search.
__global__ __launch_bounds__(128) void head(const float* __restrict__ pooled,
                                            const int* __restrict__ batch,
                                            const float* __restrict__ Wl,
                                            const float* __restrict__ bl,
                                            float* __restrict__ out) {
    const int g = blockIdx.x;
    const int j = threadIdx.x;
    __shared__ int bounds[2];
    if (j < 2) {
        int target = g + j;
        int lo = 0, hi = N;
        while (lo < hi) {
            int mid = (lo + hi) >> 1;
            if (batch[mid] < target) lo = mid + 1; else hi = mid;
        }
        bounds[j] = lo;
    }
    __syncthreads();
    float cnt = fmaxf((float)(bounds[1] - bounds[0]), 1.0f);
    float val = (pooled[g * H + j] / cnt) * Wl[j];
    __shared__ float red[128];
    red[j] = val;
    __syncthreads();
    #pragma unroll
    for (int s = 64; s > 0; s >>= 1) {
        if (j < s) red[j] += red[j + s];
        __syncthreads();
    }
    if (j == 0) out[g] = red[0] + bl[0];
}

// ---------------------------------------------------------------------------
extern "C" void kernel_launch(void* const* d_in, const int* in_sizes, int n_in,
                              void* d_out, int out_size, void* d_ws, size_t ws_size,
                              hipStream_t stream) {
    const float* x     = (const float*)d_in[0];
    const int*   ei    = (const int*)  d_in[1];   // [2, E] flat
    const int*   batch = (const int*)  d_in[2];
    const float* W1 = (const float*)d_in[4];
    const float* b1 = (const float*)d_in[5];
    const float* W2 = (const float*)d_in[6];
    const float* b2 = (const float*)d_in[7];
    const float* W3 = (const float*)d_in[8];
    const float* b3 = (const float*)d_in[9];
    const float* Wl = (const float*)d_in[10];
    const float* bl = (const float*)d_in[11];
    float* out = (float*)d_out;

    const int* row = ei;       // source
    const int* col = ei + E;   // target

    // workspace layout (256B aligned)
    auto align256 = [](size_t v) { return (v + 255) & ~(size_t)255; };
    char* ws = (char*)d_ws;
    size_t off = 0;
    int*   deg     = (int*)  (ws + off); off += align256((size_t)N * 4);
    float* dis     = (float*)(ws + off); off += align256((size_t)N * 4);
    int*   row_ptr = (int*)  (ws + off); off += align256((size_t)(N + 1) * 4);
    int*   cursor  = (int*)  (ws + off); off += align256((size_t)N * 4);
    int*   part    = (int*)  (ws + off); off += align256((size_t)NB * 4);
    int2*  csr     = (int2*) (ws + off); off += align256((size_t)E * 8);
    uint2* bufA    = (uint2*)(ws + off); off += align256((size_t)N * H * 2);   // bf16
    uint2* bufB    = (uint2*)(ws + off); off += align256((size_t)N * H * 2);   // bf16
    float* pooled  = (float*)(ws + off); off += align256((size_t)G * H * 4);
    (void)ws_size; (void)n_in; (void)in_sizes; (void)out_size;

    // --- CSR + norm precompute ---
    zero_int<<<NB, 256, 0, stream>>>(deg, N);
    count_deg<<<(E + 255) / 256, 256, 0, stream>>>(col, deg);
    dis_and_block_sum<<<NB, 256, 0, stream>>>(deg, dis, part);
    scan_part<<<1, 64, 0, stream>>>(part, row_ptr);
    scan_write<<<NB, 256, 0, stream>>>(deg, part, row_ptr, cursor);
    fill_csr<<<(E + 255) / 256, 256, 0, stream>>>(row, col, dis, cursor, csr);

    // pooled must be zero before fused_agg_pool accumulates
    zero_f32<<<(G * H + 255) / 256, 256, 0, stream>>>(pooled, G * H);

    const int gemm_grid  = N / 32;   // 1250
    const int fused_grid = N / 32;   // 1250
    const int agg3_grid  = N / 8;    // 5000

    // layer 1: t1 = x.W1 + b1  (bf16 out)
    gemm_bias<<<gemm_grid, 256, 0, stream>>>(x, W1, b1, bufA);
    // layer 2: t2 = relu(agg(t1)).W2 + b2
    fused_agg_gemm<<<fused_grid, 256, 0, stream>>>(bufA, csr, row_ptr, dis, W2, b2, bufB);
    // layer 3: t3 = relu(agg(t2)).W3 + b3
    fused_agg_gemm<<<fused_grid, 256, 0, stream>>>(bufB, csr, row_ptr, dis, W3, b3, bufA);
    // tail: pooled += relu(agg(t3)) per graph
    fused_agg_pool<<<agg3_grid, 256, 0, stream>>>(bufA, csr, row_ptr, dis, batch, pooled);
    // head
    head<<<G, 128, 0, stream>>>(pooled, batch, Wl, bl, out);
}